// Round 2
// baseline (4696.322 us; speedup 1.0000x reference)
//
#include <hip/hip_runtime.h>

// ---------------------------------------------------------------------------
// DrugGCN: 2-layer GCN (PyG GCNConv semantics) + ReLU + column mean.
//   deg[i]   = 1 + indegree(i);  dinv = rsqrt(deg)
//   h        = A @ W
//   agg[i]   = h[i]*dinv[i]^2 + b  (self-loop + bias)
//   agg[d]  += h[s]*dinv[s]*dinv[d]   for each edge (s,d)   [atomicAdd]
//   layer2 input = relu(agg1), final out = mean_i relu(agg2[i])  [256]
// ---------------------------------------------------------------------------

// --- edge-index dtype detection (int32 vs int64 in device buffer) ----------
__global__ void k_or_odd(const int* __restrict__ ei, int n_pairs, int* flag) {
    int i = blockIdx.x * 256 + threadIdx.x;
    int v = (i < n_pairs) ? ei[2 * i + 1] : 0;
    unsigned long long m = __ballot(v != 0);
    if ((threadIdx.x & 63) == 0 && m != 0ull) atomicOr(flag, 1);
}

__device__ __forceinline__ int edge_idx(const void* ei, int is64, int which,
                                        int E, int e) {
    if (is64) return (int)((const long long*)ei)[(size_t)which * E + e];
    return ((const int*)ei)[(size_t)which * E + e];
}

// --- degree / dinv ----------------------------------------------------------
__global__ void k_fill1(float* p, int n) {
    int i = blockIdx.x * 256 + threadIdx.x;
    if (i < n) p[i] = 1.0f;
}

__global__ void k_count(const void* __restrict__ ei, const int* __restrict__ flag,
                        float* deg, int E) {
    int e = blockIdx.x * 256 + threadIdx.x;
    if (e >= E) return;
    int is64 = (*flag == 0);
    int d = edge_idx(ei, is64, 1, E, e);
    atomicAdd(&deg[d], 1.0f);
}

__global__ void k_rsqrt(float* p, int n) {
    int i = blockIdx.x * 256 + threadIdx.x;
    if (i < n) p[i] = rsqrtf(p[i]);
}

// --- GEMM: C[N,K] = A[N,128] @ W[128,K], optional relu on A load ------------
// block = 256 threads -> 64 rows x 64-col tiles, 4x4 per thread.
// No unions / no dynamic vector indexing (SROA-safe: everything in VGPRs).
// xs float4-columns XOR-swizzled by (row>>2)&7 to spread LDS banks.

__device__ __forceinline__ float4 fma4(float s, float4 b, float4 c) {
    return make_float4(fmaf(s, b.x, c.x), fmaf(s, b.y, c.y),
                       fmaf(s, b.z, c.z), fmaf(s, b.w, c.w));
}

#define XS4(r, c4) xs4[(r) * 32 + ((c4) ^ (((r) >> 2) & 7))]

template <int K, bool RELU_IN>
__global__ __launch_bounds__(256) void k_gemm(const float* __restrict__ A,
                                              const float* __restrict__ W,
                                              float* __restrict__ C, int N) {
    __shared__ float xs[64 * 128];
    __shared__ float ws[128 * 64];
    float4* xs4 = reinterpret_cast<float4*>(xs);
    const int tid = threadIdx.x;
    const int row0 = blockIdx.x * 64;

    // stage x tile (64x128) as float4, swizzled columns, zero-pad OOB rows
#pragma unroll
    for (int i = 0; i < 8; ++i) {
        int idx = tid + i * 256;        // float4 index, 2048 total
        int r = idx >> 5;               // 32 float4 per row
        int c4 = idx & 31;
        float4 v = make_float4(0.f, 0.f, 0.f, 0.f);
        if (row0 + r < N) {
            v = reinterpret_cast<const float4*>(A + (size_t)(row0 + r) * 128)[c4];
            if (RELU_IN) {
                v.x = fmaxf(v.x, 0.f); v.y = fmaxf(v.y, 0.f);
                v.z = fmaxf(v.z, 0.f); v.w = fmaxf(v.w, 0.f);
            }
        }
        XS4(r, c4) = v;
    }

    const int tx = tid & 15, ty = tid >> 4;
    const int r0 = ty * 4, c0 = tx * 4;

    for (int ct = 0; ct < K / 64; ++ct) {
        __syncthreads();   // xs ready (iter 0) / prev compute done with ws
        // stage W tile (128x64)
#pragma unroll
        for (int i = 0; i < 8; ++i) {
            int idx = tid + i * 256;    // float4 index over 128*16
            int k = idx >> 4, c4 = idx & 15;
            reinterpret_cast<float4*>(ws)[idx] =
                reinterpret_cast<const float4*>(W + (size_t)k * K + ct * 64)[c4];
        }
        __syncthreads();

        float4 acc0 = make_float4(0.f, 0.f, 0.f, 0.f);
        float4 acc1 = acc0, acc2 = acc0, acc3 = acc0;
#pragma unroll
        for (int k4 = 0; k4 < 32; ++k4) {
            float4 a0 = XS4(r0 + 0, k4);
            float4 a1 = XS4(r0 + 1, k4);
            float4 a2 = XS4(r0 + 2, k4);
            float4 a3 = XS4(r0 + 3, k4);
            float4 b0 = *reinterpret_cast<const float4*>(&ws[(k4 * 4 + 0) * 64 + c0]);
            float4 b1 = *reinterpret_cast<const float4*>(&ws[(k4 * 4 + 1) * 64 + c0]);
            float4 b2 = *reinterpret_cast<const float4*>(&ws[(k4 * 4 + 2) * 64 + c0]);
            float4 b3 = *reinterpret_cast<const float4*>(&ws[(k4 * 4 + 3) * 64 + c0]);
            acc0 = fma4(a0.x, b0, acc0); acc0 = fma4(a0.y, b1, acc0);
            acc0 = fma4(a0.z, b2, acc0); acc0 = fma4(a0.w, b3, acc0);
            acc1 = fma4(a1.x, b0, acc1); acc1 = fma4(a1.y, b1, acc1);
            acc1 = fma4(a1.z, b2, acc1); acc1 = fma4(a1.w, b3, acc1);
            acc2 = fma4(a2.x, b0, acc2); acc2 = fma4(a2.y, b1, acc2);
            acc2 = fma4(a2.z, b2, acc2); acc2 = fma4(a2.w, b3, acc2);
            acc3 = fma4(a3.x, b0, acc3); acc3 = fma4(a3.y, b1, acc3);
            acc3 = fma4(a3.z, b2, acc3); acc3 = fma4(a3.w, b3, acc3);
        }

        {
            int r = row0 + r0;
            float* base = &C[(size_t)r * K + ct * 64 + c0];
            if (r + 0 < N) *reinterpret_cast<float4*>(base + (size_t)0 * K) = acc0;
            if (r + 1 < N) *reinterpret_cast<float4*>(base + (size_t)1 * K) = acc1;
            if (r + 2 < N) *reinterpret_cast<float4*>(base + (size_t)2 * K) = acc2;
            if (r + 3 < N) *reinterpret_cast<float4*>(base + (size_t)3 * K) = acc3;
        }
    }
}

// --- self-loop + bias init: agg = h * dinv[row]^2 + b -----------------------
template <int F>
__global__ void k_self(const float* __restrict__ h, const float* __restrict__ dinv,
                       const float* __restrict__ bias, float* __restrict__ agg,
                       int n4) {
    int idx = blockIdx.x * 256 + threadIdx.x;
    if (idx >= n4) return;
    constexpr int F4 = F / 4;
    int row = idx / F4;
    int c4 = idx % F4;
    float s = dinv[row];
    s *= s;
    float4 v = reinterpret_cast<const float4*>(h)[idx];
    float4 b = reinterpret_cast<const float4*>(bias)[c4];
    float4 o = make_float4(fmaf(v.x, s, b.x), fmaf(v.y, s, b.y),
                           fmaf(v.z, s, b.z), fmaf(v.w, s, b.w));
    reinterpret_cast<float4*>(agg)[idx] = o;
}

// --- edge scatter: agg[d] += h[s] * dinv[s]*dinv[d]  (wave per edge) --------
template <int F>
__global__ void k_scatter(const void* __restrict__ ei, const int* __restrict__ flag,
                          const float* __restrict__ h, const float* __restrict__ dinv,
                          float* __restrict__ agg, int E) {
    int e = blockIdx.x * 4 + (threadIdx.x >> 6);
    if (e >= E) return;
    int lane = threadIdx.x & 63;
    int is64 = (*flag == 0);
    int s = edge_idx(ei, is64, 0, E, e);
    int d = edge_idx(ei, is64, 1, E, e);
    float w = dinv[s] * dinv[d];
    const float* hs = h + (size_t)s * F;
    float* ad = agg + (size_t)d * F;
#pragma unroll
    for (int f = 0; f < F; f += 64)
        atomicAdd(&ad[f + lane], hs[f + lane] * w);
}

// --- final: out[t] = (1/N) sum_i relu(agg[i][t]),  t in [0,256) -------------
__global__ void k_mean(const float* __restrict__ agg, float* __restrict__ out,
                       int N, float invN) {
    int t = threadIdx.x;  // 256 threads = 256 columns
    float sum = 0.f;
    for (int r = blockIdx.x; r < N; r += gridDim.x)
        sum += fmaxf(agg[(size_t)r * 256 + t], 0.f);
    atomicAdd(&out[t], sum * invN);
}

// ---------------------------------------------------------------------------
extern "C" void kernel_launch(void* const* d_in, const int* in_sizes, int n_in,
                              void* d_out, int out_size, void* d_ws, size_t ws_size,
                              hipStream_t stream) {
    const float* x  = (const float*)d_in[0];
    const void*  ei = d_in[1];
    const float* W1 = (const float*)d_in[2];
    const float* b1 = (const float*)d_in[3];
    const float* W2 = (const float*)d_in[4];
    const float* b2 = (const float*)d_in[5];
    float* out = (float*)d_out;

    const int N = in_sizes[0] / 128;   // 100000
    const int E = in_sizes[1] / 2;     // 600000

    // workspace layout (all 256B aligned):
    //   [flag 256B][dinv N*4][h1 N*128*4][agg1 N*128*4][h2 N*256*4]
    //   agg2 aliases [h1;agg1] (dead by then, exactly N*256*4 bytes)
    char* ws = (char*)d_ws;
    int*   flag = (int*)ws;
    size_t off = 256;
    float* dinv = (float*)(ws + off);
    off += ((size_t)N * 4 + 255) & ~(size_t)255;
    float* h1 = (float*)(ws + off);
    float* agg2 = h1;
    off += (size_t)N * 128 * 4;
    float* agg1 = (float*)(ws + off);
    off += (size_t)N * 128 * 4;
    float* h2 = (float*)(ws + off);

    // --- edge dtype detection + degrees ---
    hipMemsetAsync(flag, 0, sizeof(int), stream);
    k_or_odd<<<(E + 255) / 256, 256, 0, stream>>>((const int*)ei, E, flag);
    k_fill1<<<(N + 255) / 256, 256, 0, stream>>>(dinv, N);
    k_count<<<(E + 255) / 256, 256, 0, stream>>>(ei, flag, dinv, E);
    k_rsqrt<<<(N + 255) / 256, 256, 0, stream>>>(dinv, N);

    // --- layer 1: h1 = x@W1; agg1 = scatter(h1)+self+b1 ---
    k_gemm<128, false><<<(N + 63) / 64, 256, 0, stream>>>(x, W1, h1, N);
    k_self<128><<<(N * 32 + 255) / 256, 256, 0, stream>>>(h1, dinv, b1, agg1, N * 32);
    k_scatter<128><<<(E + 3) / 4, 256, 0, stream>>>(ei, flag, h1, dinv, agg1, E);

    // --- layer 2: h2 = relu(agg1)@W2; agg2 = scatter(h2)+self+b2 ---
    k_gemm<256, true><<<(N + 63) / 64, 256, 0, stream>>>(agg1, W2, h2, N);
    k_self<256><<<(N * 64 + 255) / 256, 256, 0, stream>>>(h2, dinv, b2, agg2, N * 64);
    k_scatter<256><<<(E + 3) / 4, 256, 0, stream>>>(ei, flag, h2, dinv, agg2, E);

    // --- final mean of relu ---
    hipMemsetAsync(d_out, 0, (size_t)out_size * sizeof(float), stream);
    k_mean<<<512, 256, 0, stream>>>(agg2, out, N, 1.0f / (float)N);
}

// Round 3
// 1142.797 us; speedup vs baseline: 4.1095x; 4.1095x over previous
//
#include <hip/hip_runtime.h>

// ---------------------------------------------------------------------------
// DrugGCN: 2-layer GCN (PyG GCNConv semantics) + ReLU + column mean.
//   deg[i]   = 1 + indegree(i);  dinv = rsqrt(deg)
//   h        = A @ W
//   agg[i]   = h[i]*dinv[i]^2 + b  (self-loop + bias)
//   agg[d]  += h[s]*dinv[s]*dinv[d]   for each edge (s,d)   [atomicAdd]
//   layer2 input = relu(agg1), final out = mean_i relu(agg2[i])  [256]
// ---------------------------------------------------------------------------

// --- edge-index dtype detection (int32 vs int64 in device buffer) ----------
__global__ void k_or_odd(const int* __restrict__ ei, int n_pairs, int* flag) {
    int i = blockIdx.x * 256 + threadIdx.x;
    int v = (i < n_pairs) ? ei[2 * i + 1] : 0;
    unsigned long long m = __ballot(v != 0);
    if ((threadIdx.x & 63) == 0 && m != 0ull) atomicOr(flag, 1);
}

__device__ __forceinline__ int edge_idx(const void* ei, int is64, int which,
                                        int E, int e) {
    if (is64) return (int)((const long long*)ei)[(size_t)which * E + e];
    return ((const int*)ei)[(size_t)which * E + e];
}

// --- degree / dinv ----------------------------------------------------------
__global__ void k_fill1(float* p, int n) {
    int i = blockIdx.x * 256 + threadIdx.x;
    if (i < n) p[i] = 1.0f;
}

__global__ void k_count(const void* __restrict__ ei, const int* __restrict__ flag,
                        float* deg, int E) {
    int e = blockIdx.x * 256 + threadIdx.x;
    if (e >= E) return;
    int is64 = (*flag == 0);
    int d = edge_idx(ei, is64, 1, E, e);
    atomicAdd(&deg[d], 1.0f);
}

__global__ void k_rsqrt(float* p, int n) {
    int i = blockIdx.x * 256 + threadIdx.x;
    if (i < n) p[i] = rsqrtf(p[i]);
}

// --- GEMM: C[N,K] = A[N,128] @ W[128,K], optional relu on A load ------------
// block = 256 threads -> 64 rows x 64-col tiles, 4x4 per thread.
// k4 loop unroll capped at 2: full unroll (32) hoisted 256 float4 LDS loads,
// blew the 256-VGPR budget and spilled ~7 GB to scratch (R1/R2 counters).
// __launch_bounds__(256,2): cap 256 VGPR; occupancy is LDS-bound (64KB) anyway.

__device__ __forceinline__ float4 fma4(float s, float4 b, float4 c) {
    return make_float4(fmaf(s, b.x, c.x), fmaf(s, b.y, c.y),
                       fmaf(s, b.z, c.z), fmaf(s, b.w, c.w));
}

#define XS4(r, c4) xs4[(r) * 32 + ((c4) ^ (((r) >> 2) & 7))]

template <int K, bool RELU_IN>
__global__ __launch_bounds__(256, 2) void k_gemm(const float* __restrict__ A,
                                                 const float* __restrict__ W,
                                                 float* __restrict__ C, int N) {
    __shared__ float xs[64 * 128];
    __shared__ float ws[128 * 64];
    float4* xs4 = reinterpret_cast<float4*>(xs);
    const int tid = threadIdx.x;
    const int row0 = blockIdx.x * 64;

    // stage x tile (64x128) as float4, swizzled columns, zero-pad OOB rows
#pragma unroll
    for (int i = 0; i < 8; ++i) {
        int idx = tid + i * 256;        // float4 index, 2048 total
        int r = idx >> 5;               // 32 float4 per row
        int c4 = idx & 31;
        float4 v = make_float4(0.f, 0.f, 0.f, 0.f);
        if (row0 + r < N) {
            v = reinterpret_cast<const float4*>(A + (size_t)(row0 + r) * 128)[c4];
            if (RELU_IN) {
                v.x = fmaxf(v.x, 0.f); v.y = fmaxf(v.y, 0.f);
                v.z = fmaxf(v.z, 0.f); v.w = fmaxf(v.w, 0.f);
            }
        }
        XS4(r, c4) = v;
    }

    const int tx = tid & 15, ty = tid >> 4;
    const int r0 = ty * 4, c0 = tx * 4;

    for (int ct = 0; ct < K / 64; ++ct) {
        __syncthreads();   // xs ready (iter 0) / prev compute done with ws
        // stage W tile (128x64)
#pragma unroll
        for (int i = 0; i < 8; ++i) {
            int idx = tid + i * 256;    // float4 index over 128*16
            int k = idx >> 4, c4 = idx & 15;
            reinterpret_cast<float4*>(ws)[idx] =
                reinterpret_cast<const float4*>(W + (size_t)k * K + ct * 64)[c4];
        }
        __syncthreads();

        float4 acc0 = make_float4(0.f, 0.f, 0.f, 0.f);
        float4 acc1 = acc0, acc2 = acc0, acc3 = acc0;
#pragma unroll 2
        for (int k4 = 0; k4 < 32; ++k4) {
            float4 a0 = XS4(r0 + 0, k4);
            float4 a1 = XS4(r0 + 1, k4);
            float4 a2 = XS4(r0 + 2, k4);
            float4 a3 = XS4(r0 + 3, k4);
            float4 b0 = *reinterpret_cast<const float4*>(&ws[(k4 * 4 + 0) * 64 + c0]);
            float4 b1 = *reinterpret_cast<const float4*>(&ws[(k4 * 4 + 1) * 64 + c0]);
            float4 b2 = *reinterpret_cast<const float4*>(&ws[(k4 * 4 + 2) * 64 + c0]);
            float4 b3 = *reinterpret_cast<const float4*>(&ws[(k4 * 4 + 3) * 64 + c0]);
            acc0 = fma4(a0.x, b0, acc0); acc0 = fma4(a0.y, b1, acc0);
            acc0 = fma4(a0.z, b2, acc0); acc0 = fma4(a0.w, b3, acc0);
            acc1 = fma4(a1.x, b0, acc1); acc1 = fma4(a1.y, b1, acc1);
            acc1 = fma4(a1.z, b2, acc1); acc1 = fma4(a1.w, b3, acc1);
            acc2 = fma4(a2.x, b0, acc2); acc2 = fma4(a2.y, b1, acc2);
            acc2 = fma4(a2.z, b2, acc2); acc2 = fma4(a2.w, b3, acc2);
            acc3 = fma4(a3.x, b0, acc3); acc3 = fma4(a3.y, b1, acc3);
            acc3 = fma4(a3.z, b2, acc3); acc3 = fma4(a3.w, b3, acc3);
        }

        {
            int r = row0 + r0;
            float* base = &C[(size_t)r * K + ct * 64 + c0];
            if (r + 0 < N) *reinterpret_cast<float4*>(base + (size_t)0 * K) = acc0;
            if (r + 1 < N) *reinterpret_cast<float4*>(base + (size_t)1 * K) = acc1;
            if (r + 2 < N) *reinterpret_cast<float4*>(base + (size_t)2 * K) = acc2;
            if (r + 3 < N) *reinterpret_cast<float4*>(base + (size_t)3 * K) = acc3;
        }
    }
}

// --- self-loop + bias init: agg = h * dinv[row]^2 + b -----------------------
template <int F>
__global__ void k_self(const float* __restrict__ h, const float* __restrict__ dinv,
                       const float* __restrict__ bias, float* __restrict__ agg,
                       int n4) {
    int idx = blockIdx.x * 256 + threadIdx.x;
    if (idx >= n4) return;
    constexpr int F4 = F / 4;
    int row = idx / F4;
    int c4 = idx % F4;
    float s = dinv[row];
    s *= s;
    float4 v = reinterpret_cast<const float4*>(h)[idx];
    float4 b = reinterpret_cast<const float4*>(bias)[c4];
    float4 o = make_float4(fmaf(v.x, s, b.x), fmaf(v.y, s, b.y),
                           fmaf(v.z, s, b.z), fmaf(v.w, s, b.w));
    reinterpret_cast<float4*>(agg)[idx] = o;
}

// --- edge scatter: agg[d] += h[s] * dinv[s]*dinv[d]  (wave per edge) --------
template <int F>
__global__ void k_scatter(const void* __restrict__ ei, const int* __restrict__ flag,
                          const float* __restrict__ h, const float* __restrict__ dinv,
                          float* __restrict__ agg, int E) {
    int e = blockIdx.x * 4 + (threadIdx.x >> 6);
    if (e >= E) return;
    int lane = threadIdx.x & 63;
    int is64 = (*flag == 0);
    int s = edge_idx(ei, is64, 0, E, e);
    int d = edge_idx(ei, is64, 1, E, e);
    float w = dinv[s] * dinv[d];
    const float* hs = h + (size_t)s * F;
    float* ad = agg + (size_t)d * F;
#pragma unroll
    for (int f = 0; f < F; f += 64)
        atomicAdd(&ad[f + lane], hs[f + lane] * w);
}

// --- final: out[t] = (1/N) sum_i relu(agg[i][t]),  t in [0,256) -------------
__global__ void k_mean(const float* __restrict__ agg, float* __restrict__ out,
                       int N, float invN) {
    int t = threadIdx.x;  // 256 threads = 256 columns
    float sum = 0.f;
    for (int r = blockIdx.x; r < N; r += gridDim.x)
        sum += fmaxf(agg[(size_t)r * 256 + t], 0.f);
    atomicAdd(&out[t], sum * invN);
}

// ---------------------------------------------------------------------------
extern "C" void kernel_launch(void* const* d_in, const int* in_sizes, int n_in,
                              void* d_out, int out_size, void* d_ws, size_t ws_size,
                              hipStream_t stream) {
    const float* x  = (const float*)d_in[0];
    const void*  ei = d_in[1];
    const float* W1 = (const float*)d_in[2];
    const float* b1 = (const float*)d_in[3];
    const float* W2 = (const float*)d_in[4];
    const float* b2 = (const float*)d_in[5];
    float* out = (float*)d_out;

    const int N = in_sizes[0] / 128;   // 100000
    const int E = in_sizes[1] / 2;     // 600000

    // workspace layout (all 256B aligned):
    //   [flag 256B][dinv N*4][h1 N*128*4][agg1 N*128*4][h2 N*256*4]
    //   agg2 aliases [h1;agg1] (dead by then, exactly N*256*4 bytes)
    char* ws = (char*)d_ws;
    int*   flag = (int*)ws;
    size_t off = 256;
    float* dinv = (float*)(ws + off);
    off += ((size_t)N * 4 + 255) & ~(size_t)255;
    float* h1 = (float*)(ws + off);
    float* agg2 = h1;
    off += (size_t)N * 128 * 4;
    float* agg1 = (float*)(ws + off);
    off += (size_t)N * 128 * 4;
    float* h2 = (float*)(ws + off);

    // --- edge dtype detection + degrees ---
    hipMemsetAsync(flag, 0, sizeof(int), stream);
    k_or_odd<<<(E + 255) / 256, 256, 0, stream>>>((const int*)ei, E, flag);
    k_fill1<<<(N + 255) / 256, 256, 0, stream>>>(dinv, N);
    k_count<<<(E + 255) / 256, 256, 0, stream>>>(ei, flag, dinv, E);
    k_rsqrt<<<(N + 255) / 256, 256, 0, stream>>>(dinv, N);

    // --- layer 1: h1 = x@W1; agg1 = scatter(h1)+self+b1 ---
    k_gemm<128, false><<<(N + 63) / 64, 256, 0, stream>>>(x, W1, h1, N);
    k_self<128><<<(N * 32 + 255) / 256, 256, 0, stream>>>(h1, dinv, b1, agg1, N * 32);
    k_scatter<128><<<(E + 3) / 4, 256, 0, stream>>>(ei, flag, h1, dinv, agg1, E);

    // --- layer 2: h2 = relu(agg1)@W2; agg2 = scatter(h2)+self+b2 ---
    k_gemm<256, true><<<(N + 63) / 64, 256, 0, stream>>>(agg1, W2, h2, N);
    k_self<256><<<(N * 64 + 255) / 256, 256, 0, stream>>>(h2, dinv, b2, agg2, N * 64);
    k_scatter<256><<<(E + 3) / 4, 256, 0, stream>>>(ei, flag, h2, dinv, agg2, E);

    // --- final mean of relu ---
    hipMemsetAsync(d_out, 0, (size_t)out_size * sizeof(float), stream);
    k_mean<<<512, 256, 0, stream>>>(agg2, out, N, 1.0f / (float)N);
}

// Round 4
// 538.044 us; speedup vs baseline: 8.7285x; 2.1240x over previous
//
#include <hip/hip_runtime.h>

// ---------------------------------------------------------------------------
// DrugGCN restructured:
//   deg[i] = 1 + indeg(i);  dinv = rsqrt(deg)
//   CSR by dst (counts -> scan -> fill), shared by both layers.
//   Using (A_hat H) W == A_hat (H W):
//     g1  = A_hat x            [N,128]  (gather, CSR)
//     a1r = relu(g1 @ W1 + b1) [N,128]  (GEMM, fused bias+relu)
//     g2  = A_hat a1r          [N,128]  (gather, CSR)
//     out = mean_rows relu(g2 @ W2 + b2)  (GEMM fused col-reduce -> 256)
// ---------------------------------------------------------------------------

// --- edge-index dtype detection (int32 vs int64 in device buffer) ----------
__global__ void k_or_odd(const int* __restrict__ ei, int n_pairs, int* flag) {
    int i = blockIdx.x * 256 + threadIdx.x;
    int v = (i < n_pairs) ? ei[2 * i + 1] : 0;
    unsigned long long m = __ballot(v != 0);
    if ((threadIdx.x & 63) == 0 && m != 0ull) atomicOr(flag, 1);
}

__device__ __forceinline__ int edge_idx(const void* ei, int is64, int which,
                                        int E, int e) {
    if (is64) return (int)((const long long*)ei)[(size_t)which * E + e];
    return ((const int*)ei)[(size_t)which * E + e];
}

// --- degree counting (int) --------------------------------------------------
__global__ void k_zero_int(int* p, int n) {
    int i = blockIdx.x * 256 + threadIdx.x;
    if (i < n) p[i] = 0;
}

__global__ void k_count(const void* __restrict__ ei, const int* __restrict__ flag,
                        int* __restrict__ counts, int E) {
    int e = blockIdx.x * 256 + threadIdx.x;
    if (e >= E) return;
    int is64 = (*flag == 0);
    int d = edge_idx(ei, is64, 1, E, e);
    atomicAdd(&counts[d], 1);
}

__global__ void k_dinv(const int* __restrict__ counts, float* __restrict__ dinv,
                       int n) {
    int i = blockIdx.x * 256 + threadIdx.x;
    if (i < n) dinv[i] = rsqrtf(1.0f + (float)counts[i]);
}

// --- exclusive scan over counts (3 kernels) ---------------------------------
__global__ void k_scan1(const int* __restrict__ counts, int* __restrict__ offs,
                        int* __restrict__ blockSums, int n) {
    __shared__ int tmp[256];
    int t = threadIdx.x;
    int i = blockIdx.x * 256 + t;
    int my = (i < n) ? counts[i] : 0;
    tmp[t] = my;
    __syncthreads();
    for (int off = 1; off < 256; off <<= 1) {
        int v = (t >= off) ? tmp[t - off] : 0;
        __syncthreads();
        tmp[t] += v;
        __syncthreads();
    }
    if (i < n) offs[i] = tmp[t] - my;      // exclusive within block
    if (t == 255) blockSums[blockIdx.x] = tmp[255];
}

__global__ void k_scan2(int* blockSums, int nb) {
    if (threadIdx.x == 0 && blockIdx.x == 0) {
        int run = 0;
        for (int j = 0; j < nb; ++j) {
            int v = blockSums[j];
            blockSums[j] = run;
            run += v;
        }
    }
}

__global__ void k_scan3(int* __restrict__ offs, const int* __restrict__ blockSums,
                        int* __restrict__ cursor, int n) {
    int i = blockIdx.x * 256 + threadIdx.x;
    if (i < n) {
        int o = offs[i] + blockSums[blockIdx.x];
        offs[i] = o;
        cursor[i] = o;
    }
}

__global__ void k_fill_csr(const void* __restrict__ ei, const int* __restrict__ flag,
                           int* __restrict__ cursor, int* __restrict__ csr, int E) {
    int e = blockIdx.x * 256 + threadIdx.x;
    if (e >= E) return;
    int is64 = (*flag == 0);
    int s = edge_idx(ei, is64, 0, E, e);
    int d = edge_idx(ei, is64, 1, E, e);
    int pos = atomicAdd(&cursor[d], 1);
    csr[pos] = s;
}

// --- CSR gather: g[d] = h[d]*dinv[d]^2 + sum_s h[s]*dinv[s]*dinv[d] ---------
// F=128 features as 32 float4 per node; 8 nodes per 256-thread block.
__device__ __forceinline__ float4 fma4(float s, float4 b, float4 c) {
    return make_float4(fmaf(s, b.x, c.x), fmaf(s, b.y, c.y),
                       fmaf(s, b.z, c.z), fmaf(s, b.w, c.w));
}

__global__ __launch_bounds__(256) void k_gather(const float* __restrict__ h,
                                                const float* __restrict__ dinv,
                                                const int* __restrict__ offs,
                                                const int* __restrict__ counts,
                                                const int* __restrict__ csr,
                                                float* __restrict__ g, int N) {
    int node = blockIdx.x * 8 + (threadIdx.x >> 5);
    int f4 = threadIdx.x & 31;
    if (node >= N) return;
    const float4* h4 = reinterpret_cast<const float4*>(h);
    float dd = dinv[node];
    float4 acc = h4[(size_t)node * 32 + f4];
    acc.x *= dd * dd; acc.y *= dd * dd; acc.z *= dd * dd; acc.w *= dd * dd;
    int beg = offs[node], cnt = counts[node];
    for (int j = 0; j < cnt; ++j) {
        int s = csr[beg + j];
        float w = dinv[s] * dd;
        acc = fma4(w, h4[(size_t)s * 32 + f4], acc);
    }
    reinterpret_cast<float4*>(g)[(size_t)node * 32 + f4] = acc;
}

// --- GEMM machinery ---------------------------------------------------------
#define XS4(r, c4) xs4[(r) * 32 + ((c4) ^ (((r) >> 2) & 7))]

__device__ __forceinline__ float4 add4(float4 a, float4 b) {
    return make_float4(a.x + b.x, a.y + b.y, a.z + b.z, a.w + b.w);
}
__device__ __forceinline__ float4 relu4(float4 a) {
    return make_float4(fmaxf(a.x, 0.f), fmaxf(a.y, 0.f),
                       fmaxf(a.z, 0.f), fmaxf(a.w, 0.f));
}

// Shared inner machinery: stage x tile once, loop col-tiles of W.
// k_gemm_br:  C = relu(A@W + bias)  (K=128)
// k_gemm_red: partials[block] = colsum over valid rows of relu(A@W + bias) (K=256)

template <int K, bool REDUCE>
__global__ __launch_bounds__(256, 2) void k_gemm_core(const float* __restrict__ A,
                                                      const float* __restrict__ W,
                                                      const float* __restrict__ bias,
                                                      float* __restrict__ C,
                                                      float* __restrict__ partials,
                                                      int N) {
    __shared__ float xs[64 * 128];
    __shared__ float wsm[128 * 64];
    __shared__ float red[16 * 64];
    float4* xs4 = reinterpret_cast<float4*>(xs);
    const int tid = threadIdx.x;
    const int row0 = blockIdx.x * 64;

#pragma unroll
    for (int i = 0; i < 8; ++i) {
        int idx = tid + i * 256;
        int r = idx >> 5;
        int c4 = idx & 31;
        float4 v = make_float4(0.f, 0.f, 0.f, 0.f);
        if (row0 + r < N)
            v = reinterpret_cast<const float4*>(A + (size_t)(row0 + r) * 128)[c4];
        XS4(r, c4) = v;
    }

    const int tx = tid & 15, ty = tid >> 4;
    const int r0 = ty * 4, c0 = tx * 4;

    for (int ct = 0; ct < K / 64; ++ct) {
        __syncthreads();
#pragma unroll
        for (int i = 0; i < 8; ++i) {
            int idx = tid + i * 256;
            int k = idx >> 4, c4 = idx & 15;
            reinterpret_cast<float4*>(wsm)[idx] =
                reinterpret_cast<const float4*>(W + (size_t)k * K + ct * 64)[c4];
        }
        __syncthreads();

        float4 acc0 = make_float4(0.f, 0.f, 0.f, 0.f);
        float4 acc1 = acc0, acc2 = acc0, acc3 = acc0;
#pragma unroll 2
        for (int k4 = 0; k4 < 32; ++k4) {
            float4 a0 = XS4(r0 + 0, k4);
            float4 a1 = XS4(r0 + 1, k4);
            float4 a2 = XS4(r0 + 2, k4);
            float4 a3 = XS4(r0 + 3, k4);
            float4 b0 = *reinterpret_cast<const float4*>(&wsm[(k4 * 4 + 0) * 64 + c0]);
            float4 b1 = *reinterpret_cast<const float4*>(&wsm[(k4 * 4 + 1) * 64 + c0]);
            float4 b2 = *reinterpret_cast<const float4*>(&wsm[(k4 * 4 + 2) * 64 + c0]);
            float4 b3 = *reinterpret_cast<const float4*>(&wsm[(k4 * 4 + 3) * 64 + c0]);
            acc0 = fma4(a0.x, b0, acc0); acc0 = fma4(a0.y, b1, acc0);
            acc0 = fma4(a0.z, b2, acc0); acc0 = fma4(a0.w, b3, acc0);
            acc1 = fma4(a1.x, b0, acc1); acc1 = fma4(a1.y, b1, acc1);
            acc1 = fma4(a1.z, b2, acc1); acc1 = fma4(a1.w, b3, acc1);
            acc2 = fma4(a2.x, b0, acc2); acc2 = fma4(a2.y, b1, acc2);
            acc2 = fma4(a2.z, b2, acc2); acc2 = fma4(a2.w, b3, acc2);
            acc3 = fma4(a3.x, b0, acc3); acc3 = fma4(a3.y, b1, acc3);
            acc3 = fma4(a3.z, b2, acc3); acc3 = fma4(a3.w, b3, acc3);
        }

        const float4 bv = *reinterpret_cast<const float4*>(&bias[ct * 64 + c0]);
        const int r = row0 + r0;

        if (!REDUCE) {
            float* base = C + (size_t)r * K + ct * 64 + c0;
            if (r + 0 < N) *reinterpret_cast<float4*>(base + (size_t)0 * K) = relu4(add4(acc0, bv));
            if (r + 1 < N) *reinterpret_cast<float4*>(base + (size_t)1 * K) = relu4(add4(acc1, bv));
            if (r + 2 < N) *reinterpret_cast<float4*>(base + (size_t)2 * K) = relu4(add4(acc2, bv));
            if (r + 3 < N) *reinterpret_cast<float4*>(base + (size_t)3 * K) = relu4(add4(acc3, bv));
        } else {
            float4 s = make_float4(0.f, 0.f, 0.f, 0.f);
            if (r + 0 < N) s = add4(s, relu4(add4(acc0, bv)));
            if (r + 1 < N) s = add4(s, relu4(add4(acc1, bv)));
            if (r + 2 < N) s = add4(s, relu4(add4(acc2, bv)));
            if (r + 3 < N) s = add4(s, relu4(add4(acc3, bv)));
            *reinterpret_cast<float4*>(&red[ty * 64 + c0]) = s;
            __syncthreads();
            if (tid < 64) {
                float sum = 0.f;
#pragma unroll
                for (int y = 0; y < 16; ++y) sum += red[y * 64 + tid];
                partials[(size_t)blockIdx.x * K + ct * 64 + tid] = sum;
            }
            // next iteration's top-of-loop __syncthreads() protects red reuse
        }
    }
}

// --- partials reduction: [NB][256] -> [16][256] -> out[256]*invN ------------
__global__ void k_reduce1(const float* __restrict__ partials, float* __restrict__ p2,
                          int NB) {
    int c = threadIdx.x;
    float sum = 0.f;
    for (int r = blockIdx.x; r < NB; r += 16)
        sum += partials[(size_t)r * 256 + c];
    p2[blockIdx.x * 256 + c] = sum;
}

__global__ void k_reduce2(const float* __restrict__ p2, float* __restrict__ out,
                          float invN) {
    int c = threadIdx.x;
    float sum = 0.f;
#pragma unroll
    for (int b = 0; b < 16; ++b) sum += p2[b * 256 + c];
    out[c] = sum * invN;
}

// ---------------------------------------------------------------------------
extern "C" void kernel_launch(void* const* d_in, const int* in_sizes, int n_in,
                              void* d_out, int out_size, void* d_ws, size_t ws_size,
                              hipStream_t stream) {
    const float* x  = (const float*)d_in[0];
    const void*  ei = d_in[1];
    const float* W1 = (const float*)d_in[2];
    const float* b1 = (const float*)d_in[3];
    const float* W2 = (const float*)d_in[4];
    const float* b2 = (const float*)d_in[5];
    float* out = (float*)d_out;

    const int N = in_sizes[0] / 128;   // 100000
    const int E = in_sizes[1] / 2;     // 600000
    const int nb = (N + 255) / 256;    // scan blocks (391)
    const int NB = (N + 63) / 64;      // gemm row tiles (1563)

    // workspace layout (256B aligned chunks)
    char* ws = (char*)d_ws;
    size_t off = 0;
    auto alloc = [&](size_t bytes) {
        char* p = ws + off;
        off += (bytes + 255) & ~(size_t)255;
        return p;
    };
    int*   flag      = (int*)alloc(4);
    int*   counts    = (int*)alloc((size_t)N * 4);
    int*   offs      = (int*)alloc((size_t)N * 4);
    int*   cursor    = (int*)alloc((size_t)N * 4);
    int*   blockSums = (int*)alloc((size_t)nb * 4);
    float* dinv      = (float*)alloc((size_t)N * 4);
    int*   csr       = (int*)alloc((size_t)E * 4);
    float* partials  = (float*)alloc((size_t)NB * 256 * 4);
    float* p2        = (float*)alloc((size_t)16 * 256 * 4);
    float* g1        = (float*)alloc((size_t)N * 128 * 4);   // also reused as g2
    float* a1r       = (float*)alloc((size_t)N * 128 * 4);
    float* g2        = g1;

    // --- edge dtype detection + degrees + CSR ---
    hipMemsetAsync(flag, 0, sizeof(int), stream);
    k_or_odd<<<(E + 255) / 256, 256, 0, stream>>>((const int*)ei, E, flag);
    k_zero_int<<<nb, 256, 0, stream>>>(counts, N);
    k_count<<<(E + 255) / 256, 256, 0, stream>>>(ei, flag, counts, E);
    k_dinv<<<nb, 256, 0, stream>>>(counts, dinv, N);
    k_scan1<<<nb, 256, 0, stream>>>(counts, offs, blockSums, N);
    k_scan2<<<1, 64, 0, stream>>>(blockSums, nb);
    k_scan3<<<nb, 256, 0, stream>>>(offs, blockSums, cursor, N);
    k_fill_csr<<<(E + 255) / 256, 256, 0, stream>>>(ei, flag, cursor, csr, E);

    // --- layer 1: g1 = A_hat x ; a1r = relu(g1@W1 + b1) ---
    k_gather<<<(N + 7) / 8, 256, 0, stream>>>(x, dinv, offs, counts, csr, g1, N);
    k_gemm_core<128, false><<<NB, 256, 0, stream>>>(g1, W1, b1, a1r, nullptr, N);

    // --- layer 2: g2 = A_hat a1r ; out = mean relu(g2@W2 + b2) ---
    k_gather<<<(N + 7) / 8, 256, 0, stream>>>(a1r, dinv, offs, counts, csr, g2, N);
    k_gemm_core<256, true><<<NB, 256, 0, stream>>>(g2, W2, b2, nullptr, partials, N);
    k_reduce1<<<16, 256, 0, stream>>>(partials, p2, NB);
    k_reduce2<<<1, 256, 0, stream>>>(p2, out, 1.0f / (float)N);
}

// Round 5
// 502.286 us; speedup vs baseline: 9.3499x; 1.0712x over previous
//
#include <hip/hip_runtime.h>

// ---------------------------------------------------------------------------
// DrugGCN, bf16-MFMA pipeline:
//   CSR by dst (counts -> scan -> fill) once per call.
//   xb  = bf16(x)
//   g1  = A_hat xb           [N,128] bf16   (CSR gather, f32 accum)
//   a1r = relu(g1@W1 + b1)   [N,128] bf16   (MFMA GEMM, fused epilogue)
//   g2  = A_hat a1r          [N,128] bf16   (gather)
//   out = mean_rows relu(g2@W2 + b2)        (MFMA GEMM, fused col-reduce)
// W pre-transposed+converted to WT[n][k] bf16 so B-fragments are 16B loads.
// ---------------------------------------------------------------------------

typedef __attribute__((ext_vector_type(8))) short short8;
typedef __attribute__((ext_vector_type(4))) float f32x4;

__device__ __forceinline__ float b2f(unsigned short u) {
    union { unsigned int i; float f; } c;
    c.i = ((unsigned int)u) << 16;
    return c.f;
}
__device__ __forceinline__ unsigned short f2b(float x) {
    union { float f; unsigned int i; } c;
    c.f = x;
    unsigned int r = c.i + 0x7FFFu + ((c.i >> 16) & 1u);   // RNE
    return (unsigned short)(r >> 16);
}

// --- edge-index dtype detection (int32 vs int64 in device buffer) ----------
__global__ void k_or_odd(const int* __restrict__ ei, int n_pairs, int* flag) {
    int i = blockIdx.x * 256 + threadIdx.x;
    int v = (i < n_pairs) ? ei[2 * i + 1] : 0;
    unsigned long long m = __ballot(v != 0);
    if ((threadIdx.x & 63) == 0 && m != 0ull) atomicOr(flag, 1);
}

__device__ __forceinline__ int edge_idx(const void* ei, int is64, int which,
                                        int E, int e) {
    if (is64) return (int)((const long long*)ei)[(size_t)which * E + e];
    return ((const int*)ei)[(size_t)which * E + e];
}

// --- degree counting (int) --------------------------------------------------
__global__ void k_zero_int(int* p, int n) {
    int i = blockIdx.x * 256 + threadIdx.x;
    if (i < n) p[i] = 0;
}

__global__ void k_count(const void* __restrict__ ei, const int* __restrict__ flag,
                        int* __restrict__ counts, int E) {
    int e = blockIdx.x * 256 + threadIdx.x;
    if (e >= E) return;
    int is64 = (*flag == 0);
    int d = edge_idx(ei, is64, 1, E, e);
    atomicAdd(&counts[d], 1);
}

__global__ void k_dinv(const int* __restrict__ counts, float* __restrict__ dinv,
                       int n) {
    int i = blockIdx.x * 256 + threadIdx.x;
    if (i < n) dinv[i] = rsqrtf(1.0f + (float)counts[i]);
}

// --- exclusive scan over counts (3 kernels) ---------------------------------
__global__ void k_scan1(const int* __restrict__ counts, int* __restrict__ offs,
                        int* __restrict__ blockSums, int n) {
    __shared__ int tmp[256];
    int t = threadIdx.x;
    int i = blockIdx.x * 256 + t;
    int my = (i < n) ? counts[i] : 0;
    tmp[t] = my;
    __syncthreads();
    for (int off = 1; off < 256; off <<= 1) {
        int v = (t >= off) ? tmp[t - off] : 0;
        __syncthreads();
        tmp[t] += v;
        __syncthreads();
    }
    if (i < n) offs[i] = tmp[t] - my;
    if (t == 255) blockSums[blockIdx.x] = tmp[255];
}

__global__ void k_scan2(int* blockSums, int nb) {
    if (threadIdx.x == 0 && blockIdx.x == 0) {
        int run = 0;
        for (int j = 0; j < nb; ++j) {
            int v = blockSums[j];
            blockSums[j] = run;
            run += v;
        }
    }
}

__global__ void k_scan3(int* __restrict__ offs, const int* __restrict__ blockSums,
                        int* __restrict__ cursor, int n) {
    int i = blockIdx.x * 256 + threadIdx.x;
    if (i < n) {
        int o = offs[i] + blockSums[blockIdx.x];
        offs[i] = o;
        cursor[i] = o;
    }
}

__global__ void k_fill_csr(const void* __restrict__ ei, const int* __restrict__ flag,
                           int* __restrict__ cursor, int* __restrict__ csr, int E) {
    int e = blockIdx.x * 256 + threadIdx.x;
    if (e >= E) return;
    int is64 = (*flag == 0);
    int s = edge_idx(ei, is64, 0, E, e);
    int d = edge_idx(ei, is64, 1, E, e);
    int pos = atomicAdd(&cursor[d], 1);
    csr[pos] = s;
}

// --- conversions ------------------------------------------------------------
__global__ void k_cvt_x(const float* __restrict__ x, unsigned short* __restrict__ xb,
                        int n4) {
    int i = blockIdx.x * 256 + threadIdx.x;
    if (i >= n4) return;
    float4 v = reinterpret_cast<const float4*>(x)[i];
    ushort4 o;
    o.x = f2b(v.x); o.y = f2b(v.y); o.z = f2b(v.z); o.w = f2b(v.w);
    reinterpret_cast<ushort4*>(xb)[i] = o;
}

// W[k][n] (f32, KIN=128 rows, KOUT cols) -> WT[n][k] (bf16)
__global__ void k_cvt_wt(const float* __restrict__ W, unsigned short* __restrict__ WT,
                         int KOUT, int total) {
    int idx = blockIdx.x * 256 + threadIdx.x;
    if (idx >= total) return;
    int k = idx / KOUT, n = idx % KOUT;
    WT[(size_t)n * 128 + k] = f2b(W[idx]);
}

// --- CSR gather (bf16 rows, f32 accum): g[d] = dd^2 h[d] + sum dinv[s] dd h[s]
__global__ __launch_bounds__(256) void k_gather_b(const unsigned short* __restrict__ h,
                                                  const float* __restrict__ dinv,
                                                  const int* __restrict__ offs,
                                                  const int* __restrict__ counts,
                                                  const int* __restrict__ csr,
                                                  unsigned short* __restrict__ g,
                                                  int N) {
    int node = blockIdx.x * 8 + (threadIdx.x >> 5);
    int f4 = threadIdx.x & 31;          // 4 bf16 (8B) per lane, 32 lanes = 256B row
    if (node >= N) return;
    const ushort4* h4 = reinterpret_cast<const ushort4*>(h);
    float dd = dinv[node];
    float w0 = dd * dd;
    ushort4 sv = h4[(size_t)node * 32 + f4];
    float ax = b2f(sv.x) * w0, ay = b2f(sv.y) * w0;
    float az = b2f(sv.z) * w0, aw = b2f(sv.w) * w0;
    int beg = offs[node], cnt = counts[node];
    for (int j = 0; j < cnt; ++j) {
        int s = csr[beg + j];
        float w = dinv[s] * dd;
        ushort4 v = h4[(size_t)s * 32 + f4];
        ax = fmaf(b2f(v.x), w, ax); ay = fmaf(b2f(v.y), w, ay);
        az = fmaf(b2f(v.z), w, az); aw = fmaf(b2f(v.w), w, aw);
    }
    ushort4 o;
    o.x = f2b(ax); o.y = f2b(ay); o.z = f2b(az); o.w = f2b(aw);
    reinterpret_cast<ushort4*>(g)[(size_t)node * 32 + f4] = o;
}

// --- MFMA GEMM: A[N,128]bf16 @ WT^T -> relu(+bias), store bf16 OR col-reduce
// 256 thr = 4 waves; block tile 64 rows; wave tile 16 rows x KOUT cols.
// Fragment mapping (16x16x32, m89-verified): A: row=lane&15, k=(lane>>4)*8+j;
// B: col=lane&15, k=(lane>>4)*8+j (WT[n][k] rows are contiguous 16B);
// D: col=lane&15, row=(lane>>4)*4+r.
template <int KOUT, bool REDUCE>
__global__ __launch_bounds__(256) void k_mgemm(const unsigned short* __restrict__ A,
                                               const unsigned short* __restrict__ WT,
                                               const float* __restrict__ bias,
                                               unsigned short* __restrict__ C,
                                               float* __restrict__ partials, int N) {
    __shared__ float red[4][256];
    const int tid = threadIdx.x;
    const int wave = tid >> 6, lane = tid & 63;
    const int l15 = lane & 15, lg = lane >> 4;
    const int arow = blockIdx.x * 64 + wave * 16 + l15;
    constexpr int NF = KOUT / 16;
    f32x4 acc[NF];
#pragma unroll
    for (int nf = 0; nf < NF; ++nf) acc[nf] = (f32x4){0.f, 0.f, 0.f, 0.f};

    for (int kk = 0; kk < 4; ++kk) {    // KIN = 128 = 4 * 32 (kept rolled: R2 lesson)
        short8 a = (short8){0, 0, 0, 0, 0, 0, 0, 0};
        if (arow < N)
            a = *reinterpret_cast<const short8*>(A + (size_t)arow * 128 + kk * 32 + lg * 8);
#pragma unroll
        for (int nf = 0; nf < NF; ++nf) {
            short8 b = *reinterpret_cast<const short8*>(
                WT + (size_t)(nf * 16 + l15) * 128 + kk * 32 + lg * 8);
            acc[nf] = __builtin_amdgcn_mfma_f32_16x16x32_bf16(a, b, acc[nf], 0, 0, 0);
        }
    }

    const int orow = blockIdx.x * 64 + wave * 16 + lg * 4;
    if (!REDUCE) {
#pragma unroll
        for (int nf = 0; nf < NF; ++nf) {
            int col = nf * 16 + l15;
            float bv = bias[col];
#pragma unroll
            for (int r = 0; r < 4; ++r) {
                int rr = orow + r;
                if (rr < N)
                    C[(size_t)rr * KOUT + col] = f2b(fmaxf(acc[nf][r] + bv, 0.f));
            }
        }
    } else {
#pragma unroll
        for (int nf = 0; nf < NF; ++nf) {
            int col = nf * 16 + l15;
            float bv = bias[col];
            float s = 0.f;
#pragma unroll
            for (int r = 0; r < 4; ++r) {
                int rr = orow + r;
                if (rr < N) s += fmaxf(acc[nf][r] + bv, 0.f);
            }
            s += __shfl_xor(s, 16);
            s += __shfl_xor(s, 32);
            if (lg == 0) red[wave][col] = s;
        }
        __syncthreads();
        float p = red[0][tid] + red[1][tid] + red[2][tid] + red[3][tid];
        partials[(size_t)blockIdx.x * KOUT + tid] = p;
    }
}

// --- partials reduction: [NB][256] -> [16][256] -> out[256]*invN ------------
__global__ void k_reduce1(const float* __restrict__ partials, float* __restrict__ p2,
                          int NB) {
    int c = threadIdx.x;
    float sum = 0.f;
    for (int r = blockIdx.x; r < NB; r += 16)
        sum += partials[(size_t)r * 256 + c];
    p2[blockIdx.x * 256 + c] = sum;
}

__global__ void k_reduce2(const float* __restrict__ p2, float* __restrict__ out,
                          float invN) {
    int c = threadIdx.x;
    float sum = 0.f;
#pragma unroll
    for (int b = 0; b < 16; ++b) sum += p2[b * 256 + c];
    out[c] = sum * invN;
}

// ---------------------------------------------------------------------------
extern "C" void kernel_launch(void* const* d_in, const int* in_sizes, int n_in,
                              void* d_out, int out_size, void* d_ws, size_t ws_size,
                              hipStream_t stream) {
    const float* x  = (const float*)d_in[0];
    const void*  ei = d_in[1];
    const float* W1 = (const float*)d_in[2];
    const float* b1 = (const float*)d_in[3];
    const float* W2 = (const float*)d_in[4];
    const float* b2 = (const float*)d_in[5];
    float* out = (float*)d_out;

    const int N = in_sizes[0] / 128;   // 100000
    const int E = in_sizes[1] / 2;     // 600000
    const int nb = (N + 255) / 256;
    const int NB = (N + 63) / 64;      // gemm row tiles

    char* ws = (char*)d_ws;
    size_t off = 0;
    auto alloc = [&](size_t bytes) {
        char* p = ws + off;
        off += (bytes + 255) & ~(size_t)255;
        return p;
    };
    int*            flag      = (int*)alloc(4);
    int*            counts    = (int*)alloc((size_t)N * 4);
    int*            offs      = (int*)alloc((size_t)N * 4);
    int*            cursor    = (int*)alloc((size_t)N * 4);
    int*            blockSums = (int*)alloc((size_t)nb * 4);
    float*          dinv      = (float*)alloc((size_t)N * 4);
    int*            csr       = (int*)alloc((size_t)E * 4);
    float*          partials  = (float*)alloc((size_t)NB * 256 * 4);
    float*          p2        = (float*)alloc((size_t)16 * 256 * 4);
    unsigned short* wt1       = (unsigned short*)alloc((size_t)128 * 128 * 2);
    unsigned short* wt2       = (unsigned short*)alloc((size_t)256 * 128 * 2);
    unsigned short* xb        = (unsigned short*)alloc((size_t)N * 128 * 2);
    unsigned short* g1        = (unsigned short*)alloc((size_t)N * 128 * 2);
    unsigned short* a1r       = (unsigned short*)alloc((size_t)N * 128 * 2);
    unsigned short* g2        = xb;    // xb dead after gather1

    // --- edge dtype detection + degrees + CSR ---
    hipMemsetAsync(flag, 0, sizeof(int), stream);
    k_or_odd<<<(E + 255) / 256, 256, 0, stream>>>((const int*)ei, E, flag);
    k_zero_int<<<nb, 256, 0, stream>>>(counts, N);
    k_count<<<(E + 255) / 256, 256, 0, stream>>>(ei, flag, counts, E);
    k_dinv<<<nb, 256, 0, stream>>>(counts, dinv, N);
    k_scan1<<<nb, 256, 0, stream>>>(counts, offs, blockSums, N);
    k_scan2<<<1, 64, 0, stream>>>(blockSums, nb);
    k_scan3<<<nb, 256, 0, stream>>>(offs, blockSums, cursor, N);
    k_fill_csr<<<(E + 255) / 256, 256, 0, stream>>>(ei, flag, cursor, csr, E);

    // --- conversions ---
    k_cvt_x<<<(N * 32 + 255) / 256, 256, 0, stream>>>(x, xb, N * 32);
    k_cvt_wt<<<(128 * 128 + 255) / 256, 256, 0, stream>>>(W1, wt1, 128, 128 * 128);
    k_cvt_wt<<<(128 * 256 + 255) / 256, 256, 0, stream>>>(W2, wt2, 256, 128 * 256);

    // --- layer 1 ---
    k_gather_b<<<(N + 7) / 8, 256, 0, stream>>>(xb, dinv, offs, counts, csr, g1, N);
    k_mgemm<128, false><<<NB, 256, 0, stream>>>(g1, wt1, b1, a1r, nullptr, N);

    // --- layer 2 + fused mean ---
    k_gather_b<<<(N + 7) / 8, 256, 0, stream>>>(a1r, dinv, offs, counts, csr, g2, N);
    k_mgemm<256, true><<<NB, 256, 0, stream>>>(g2, wt2, b2, nullptr, partials, N);
    k_reduce1<<<16, 256, 0, stream>>>(partials, p2, NB);
    k_reduce2<<<1, 256, 0, stream>>>(p2, out, 1.0f / (float)N);
}

// Round 6
// 314.891 us; speedup vs baseline: 14.9141x; 1.5951x over previous
//
#include <hip/hip_runtime.h>

// ---------------------------------------------------------------------------
// DrugGCN, bf16-MFMA pipeline:
//   CSR by dst (counts -> scan -> fill) once per call.
//   xb  = bf16(x)
//   g1  = A_hat xb           [N,128] bf16   (CSR gather, f32 accum)
//   a1r = relu(g1@W1 + b1)   [N,128] bf16   (MFMA GEMM, fused epilogue)
//   g2  = A_hat a1r          [N,128] bf16   (gather)
//   out = mean_rows relu(g2@W2 + b2)        (MFMA GEMM, fused col-reduce)
// W pre-transposed+converted to WT[n][k] bf16 so B-fragments are 16B loads.
// R5 lessons: edge buffer is int32 in practice (JAX x64-off downcast) ->
// full-scan detector's same-address atomicOr storm cost 108us; sample instead.
// Serial scan2 (1 thread x 391 dependent loads) parallelized.
// ---------------------------------------------------------------------------

typedef __attribute__((ext_vector_type(8))) short short8;
typedef __attribute__((ext_vector_type(4))) float f32x4;

__device__ __forceinline__ float b2f(unsigned short u) {
    union { unsigned int i; float f; } c;
    c.i = ((unsigned int)u) << 16;
    return c.f;
}
__device__ __forceinline__ unsigned short f2b(float x) {
    union { float f; unsigned int i; } c;
    c.f = x;
    unsigned int r = c.i + 0x7FFFu + ((c.i >> 16) & 1u);   // RNE
    return (unsigned short)(r >> 16);
}

// --- edge-index dtype detection, sampled (single block, no atomics) ---------
// int64 little-endian indices < 2^31  =>  every odd 32-bit word is 0.
// int32 random node ids: P(sampled word==0) = 1/N; 1024 samples -> certainty.
__global__ void k_detect(const int* __restrict__ ei, int E, int* __restrict__ flag) {
    __shared__ int anyv[4];
    int t = threadIdx.x;                 // 256 threads, 4 samples each
    int v = 0;
#pragma unroll
    for (int r = 0; r < 4; ++r) {
        long long k = (long long)(t * 4 + r) * E >> 10;   // spread over [0,E)
        v |= ei[2 * (int)k + 1];
    }
    unsigned long long m = __ballot(v != 0);
    if ((t & 63) == 0) anyv[t >> 6] = (m != 0ull) ? 1 : 0;
    __syncthreads();
    if (t == 0) flag[0] = anyv[0] | anyv[1] | anyv[2] | anyv[3];
}

__device__ __forceinline__ int edge_idx(const void* ei, int is64, int which,
                                        int E, int e) {
    if (is64) return (int)((const long long*)ei)[(size_t)which * E + e];
    return ((const int*)ei)[(size_t)which * E + e];
}

// --- degree counting (int) --------------------------------------------------
__global__ void k_zero_int(int* p, int n) {
    int i = blockIdx.x * 256 + threadIdx.x;
    if (i < n) p[i] = 0;
}

__global__ void k_count(const void* __restrict__ ei, const int* __restrict__ flag,
                        int* __restrict__ counts, int E) {
    int e = blockIdx.x * 256 + threadIdx.x;
    if (e >= E) return;
    int is64 = (*flag == 0);
    int d = edge_idx(ei, is64, 1, E, e);
    atomicAdd(&counts[d], 1);
}

__global__ void k_dinv(const int* __restrict__ counts, float* __restrict__ dinv,
                       int n) {
    int i = blockIdx.x * 256 + threadIdx.x;
    if (i < n) dinv[i] = rsqrtf(1.0f + (float)counts[i]);
}

// --- exclusive scan over counts (3 kernels) ---------------------------------
__global__ void k_scan1(const int* __restrict__ counts, int* __restrict__ offs,
                        int* __restrict__ blockSums, int n) {
    __shared__ int tmp[256];
    int t = threadIdx.x;
    int i = blockIdx.x * 256 + t;
    int my = (i < n) ? counts[i] : 0;
    tmp[t] = my;
    __syncthreads();
    for (int off = 1; off < 256; off <<= 1) {
        int v = (t >= off) ? tmp[t - off] : 0;
        __syncthreads();
        tmp[t] += v;
        __syncthreads();
    }
    if (i < n) offs[i] = tmp[t] - my;
    if (t == 255) blockSums[blockIdx.x] = tmp[255];
}

// single-block 512-thread Hillis-Steele scan (exclusive), carry over tiles
__global__ void k_scan2(int* __restrict__ blockSums, int nb) {
    __shared__ int tmp[512];
    __shared__ int carry;
    int t = threadIdx.x;
    if (t == 0) carry = 0;
    __syncthreads();
    for (int base = 0; base < nb; base += 512) {
        int i = base + t;
        int my = (i < nb) ? blockSums[i] : 0;
        tmp[t] = my;
        __syncthreads();
        for (int off = 1; off < 512; off <<= 1) {
            int v = (t >= off) ? tmp[t - off] : 0;
            __syncthreads();
            tmp[t] += v;
            __syncthreads();
        }
        if (i < nb) blockSums[i] = carry + tmp[t] - my;   // exclusive
        __syncthreads();
        if (t == 0) carry += tmp[511];
        __syncthreads();
    }
}

__global__ void k_scan3(int* __restrict__ offs, const int* __restrict__ blockSums,
                        int* __restrict__ cursor, int n) {
    int i = blockIdx.x * 256 + threadIdx.x;
    if (i < n) {
        int o = offs[i] + blockSums[blockIdx.x];
        offs[i] = o;
        cursor[i] = o;
    }
}

__global__ void k_fill_csr(const void* __restrict__ ei, const int* __restrict__ flag,
                           int* __restrict__ cursor, int* __restrict__ csr, int E) {
    int e = blockIdx.x * 256 + threadIdx.x;
    if (e >= E) return;
    int is64 = (*flag == 0);
    int s = edge_idx(ei, is64, 0, E, e);
    int d = edge_idx(ei, is64, 1, E, e);
    int pos = atomicAdd(&cursor[d], 1);
    csr[pos] = s;
}

// --- conversions ------------------------------------------------------------
__global__ void k_cvt_x(const float* __restrict__ x, unsigned short* __restrict__ xb,
                        int n4) {
    int i = blockIdx.x * 256 + threadIdx.x;
    if (i >= n4) return;
    float4 v = reinterpret_cast<const float4*>(x)[i];
    ushort4 o;
    o.x = f2b(v.x); o.y = f2b(v.y); o.z = f2b(v.z); o.w = f2b(v.w);
    reinterpret_cast<ushort4*>(xb)[i] = o;
}

// W[k][n] (f32, KIN=128 rows, KOUT cols) -> WT[n][k] (bf16)
__global__ void k_cvt_wt(const float* __restrict__ W, unsigned short* __restrict__ WT,
                         int KOUT, int total) {
    int idx = blockIdx.x * 256 + threadIdx.x;
    if (idx >= total) return;
    int k = idx / KOUT, n = idx % KOUT;
    WT[(size_t)n * 128 + k] = f2b(W[idx]);
}

// --- CSR gather (bf16 rows, f32 accum): g[d] = dd^2 h[d] + sum dinv[s] dd h[s]
// 16 lanes/node, short8 (16B) loads; 16 nodes per 256-thread block.
__global__ __launch_bounds__(256) void k_gather_b(const unsigned short* __restrict__ h,
                                                  const float* __restrict__ dinv,
                                                  const int* __restrict__ offs,
                                                  const int* __restrict__ counts,
                                                  const int* __restrict__ csr,
                                                  unsigned short* __restrict__ g,
                                                  int N) {
    int node = blockIdx.x * 16 + (threadIdx.x >> 4);
    int l16 = threadIdx.x & 15;         // 8 bf16 (16B) per lane, 16 lanes = 256B row
    if (node >= N) return;
    const short8* h8 = reinterpret_cast<const short8*>(h);
    float dd = dinv[node];
    float w0 = dd * dd;
    size_t rowu = (size_t)node * 16 + l16;
    short8 sv = h8[rowu];
    float a[8];
#pragma unroll
    for (int j = 0; j < 8; ++j) a[j] = b2f((unsigned short)sv[j]) * w0;
    int beg = offs[node], cnt = counts[node];
    for (int e = 0; e < cnt; ++e) {
        int s = csr[beg + e];
        float w = dinv[s] * dd;
        short8 v = h8[(size_t)s * 16 + l16];
#pragma unroll
        for (int j = 0; j < 8; ++j) a[j] = fmaf(b2f((unsigned short)v[j]), w, a[j]);
    }
    short8 o;
#pragma unroll
    for (int j = 0; j < 8; ++j) o[j] = (short)f2b(a[j]);
    reinterpret_cast<short8*>(g)[rowu] = o;
}

// --- MFMA GEMM: A[N,128]bf16 @ WT^T -> relu(+bias), store bf16 OR col-reduce
// 256 thr = 4 waves; block tile 64 rows; wave tile 16 rows x KOUT cols.
// Fragment mapping (16x16x32, m89-verified): A: row=lane&15, k=(lane>>4)*8+j;
// B: col=lane&15, k=(lane>>4)*8+j (WT[n][k] rows are contiguous 16B);
// D: col=lane&15, row=(lane>>4)*4+r.
template <int KOUT, bool REDUCE>
__global__ __launch_bounds__(256) void k_mgemm(const unsigned short* __restrict__ A,
                                               const unsigned short* __restrict__ WT,
                                               const float* __restrict__ bias,
                                               unsigned short* __restrict__ C,
                                               float* __restrict__ partials, int N) {
    __shared__ float red[4][256];
    const int tid = threadIdx.x;
    const int wave = tid >> 6, lane = tid & 63;
    const int l15 = lane & 15, lg = lane >> 4;
    const int arow = blockIdx.x * 64 + wave * 16 + l15;
    constexpr int NF = KOUT / 16;
    f32x4 acc[NF];
#pragma unroll
    for (int nf = 0; nf < NF; ++nf) acc[nf] = (f32x4){0.f, 0.f, 0.f, 0.f};

    for (int kk = 0; kk < 4; ++kk) {    // KIN = 128 = 4 * 32 (kept rolled: R2 lesson)
        short8 a = (short8){0, 0, 0, 0, 0, 0, 0, 0};
        if (arow < N)
            a = *reinterpret_cast<const short8*>(A + (size_t)arow * 128 + kk * 32 + lg * 8);
#pragma unroll
        for (int nf = 0; nf < NF; ++nf) {
            short8 b = *reinterpret_cast<const short8*>(
                WT + (size_t)(nf * 16 + l15) * 128 + kk * 32 + lg * 8);
            acc[nf] = __builtin_amdgcn_mfma_f32_16x16x32_bf16(a, b, acc[nf], 0, 0, 0);
        }
    }

    const int orow = blockIdx.x * 64 + wave * 16 + lg * 4;
    if (!REDUCE) {
#pragma unroll
        for (int nf = 0; nf < NF; ++nf) {
            int col = nf * 16 + l15;
            float bv = bias[col];
#pragma unroll
            for (int r = 0; r < 4; ++r) {
                int rr = orow + r;
                if (rr < N)
                    C[(size_t)rr * KOUT + col] = f2b(fmaxf(acc[nf][r] + bv, 0.f));
            }
        }
    } else {
#pragma unroll
        for (int nf = 0; nf < NF; ++nf) {
            int col = nf * 16 + l15;
            float bv = bias[col];
            float s = 0.f;
#pragma unroll
            for (int r = 0; r < 4; ++r) {
                int rr = orow + r;
                if (rr < N) s += fmaxf(acc[nf][r] + bv, 0.f);
            }
            s += __shfl_xor(s, 16);
            s += __shfl_xor(s, 32);
            if (lg == 0) red[wave][col] = s;
        }
        __syncthreads();
        float p = red[0][tid] + red[1][tid] + red[2][tid] + red[3][tid];
        partials[(size_t)blockIdx.x * KOUT + tid] = p;
    }
}

// --- partials reduction: [NB][256] -> [16][256] -> out[256]*invN ------------
__global__ void k_reduce1(const float* __restrict__ partials, float* __restrict__ p2,
                          int NB) {
    int c = threadIdx.x;
    float sum = 0.f;
    for (int r = blockIdx.x; r < NB; r += 16)
        sum += partials[(size_t)r * 256 + c];
    p2[blockIdx.x * 256 + c] = sum;
}

__global__ void k_reduce2(const float* __restrict__ p2, float* __restrict__ out,
                          float invN) {
    int c = threadIdx.x;
    float sum = 0.f;
#pragma unroll
    for (int b = 0; b < 16; ++b) sum += p2[b * 256 + c];
    out[c] = sum * invN;
}

// ---------------------------------------------------------------------------
extern "C" void kernel_launch(void* const* d_in, const int* in_sizes, int n_in,
                              void* d_out, int out_size, void* d_ws, size_t ws_size,
                              hipStream_t stream) {
    const float* x  = (const float*)d_in[0];
    const void*  ei = d_in[1];
    const float* W1 = (const float*)d_in[2];
    const float* b1 = (const float*)d_in[3];
    const float* W2 = (const float*)d_in[4];
    const float* b2 = (const float*)d_in[5];
    float* out = (float*)d_out;

    const int N = in_sizes[0] / 128;   // 100000
    const int E = in_sizes[1] / 2;     // 600000
    const int nb = (N + 255) / 256;
    const int NB = (N + 63) / 64;      // gemm row tiles

    char* ws = (char*)d_ws;
    size_t off = 0;
    auto alloc = [&](size_t bytes) {
        char* p = ws + off;
        off += (bytes + 255) & ~(size_t)255;
        return p;
    };
    int*            flag      = (int*)alloc(4);
    int*            counts    = (int*)alloc((size_t)N * 4);
    int*            offs      = (int*)alloc((size_t)N * 4);
    int*            cursor    = (int*)alloc((size_t)N * 4);
    int*            blockSums = (int*)alloc((size_t)nb * 4);
    float*          dinv      = (float*)alloc((size_t)N * 4);
    int*            csr       = (int*)alloc((size_t)E * 4);
    float*          partials  = (float*)alloc((size_t)NB * 256 * 4);
    float*          p2        = (float*)alloc((size_t)16 * 256 * 4);
    unsigned short* wt1       = (unsigned short*)alloc((size_t)128 * 128 * 2);
    unsigned short* wt2       = (unsigned short*)alloc((size_t)256 * 128 * 2);
    unsigned short* xb        = (unsigned short*)alloc((size_t)N * 128 * 2);
    unsigned short* g1        = (unsigned short*)alloc((size_t)N * 128 * 2);
    unsigned short* a1r       = (unsigned short*)alloc((size_t)N * 128 * 2);
    unsigned short* g2        = xb;    // xb dead after gather1

    // --- edge dtype detection + degrees + CSR ---
    k_detect<<<1, 256, 0, stream>>>((const int*)ei, E, flag);
    k_zero_int<<<nb, 256, 0, stream>>>(counts, N);
    k_count<<<(E + 255) / 256, 256, 0, stream>>>(ei, flag, counts, E);
    k_dinv<<<nb, 256, 0, stream>>>(counts, dinv, N);
    k_scan1<<<nb, 256, 0, stream>>>(counts, offs, blockSums, N);
    k_scan2<<<1, 512, 0, stream>>>(blockSums, nb);
    k_scan3<<<nb, 256, 0, stream>>>(offs, blockSums, cursor, N);
    k_fill_csr<<<(E + 255) / 256, 256, 0, stream>>>(ei, flag, cursor, csr, E);

    // --- conversions ---
    k_cvt_x<<<(N * 32 + 255) / 256, 256, 0, stream>>>(x, xb, N * 32);
    k_cvt_wt<<<(128 * 128 + 255) / 256, 256, 0, stream>>>(W1, wt1, 128, 128 * 128);
    k_cvt_wt<<<(128 * 256 + 255) / 256, 256, 0, stream>>>(W2, wt2, 256, 128 * 256);

    // --- layer 1 ---
    k_gather_b<<<(N + 15) / 16, 256, 0, stream>>>(xb, dinv, offs, counts, csr, g1, N);
    k_mgemm<128, false><<<NB, 256, 0, stream>>>(g1, wt1, b1, a1r, nullptr, N);

    // --- layer 2 + fused mean ---
    k_gather_b<<<(N + 15) / 16, 256, 0, stream>>>(a1r, dinv, offs, counts, csr, g2, N);
    k_mgemm<256, true><<<NB, 256, 0, stream>>>(g2, wt2, b2, nullptr, partials, N);
    k_reduce1<<<16, 256, 0, stream>>>(partials, p2, NB);
    k_reduce2<<<1, 256, 0, stream>>>(p2, out, 1.0f / (float)N);
}

// Round 7
// 240.622 us; speedup vs baseline: 19.5175x; 1.3087x over previous
//
#include <hip/hip_runtime.h>

// ---------------------------------------------------------------------------
// DrugGCN, bf16-MFMA pipeline:
//   CSR by dst (counts -> scan -> fill) once per call.
//   xb  = bf16(x)
//   g1  = A_hat xb           [N,128] bf16   (CSR gather, f32 accum)
//   a1r = relu(g1@W1 + b1)   [N,128] bf16   (B-stationary MFMA GEMM)
//   g2  = A_hat a1r          [N,128] bf16   (gather)
//   out = mean_rows relu(g2@W2 + b2)        (B-stationary GEMM, fused reduce)
// R6 lesson: streaming WT from L2 per-MFMA was latency-bound (66us, all pipes
// idle). Now each wave owns KOUT/4 cols and keeps ALL its B fragments in
// registers (<=64 VGPR); inner loop is 4 A-loads + 4*NFW MFMAs per 16 rows.
// ---------------------------------------------------------------------------

typedef __attribute__((ext_vector_type(8))) short short8;
typedef __attribute__((ext_vector_type(4))) float f32x4;

__device__ __forceinline__ float b2f(unsigned short u) {
    union { unsigned int i; float f; } c;
    c.i = ((unsigned int)u) << 16;
    return c.f;
}
__device__ __forceinline__ unsigned short f2b(float x) {
    union { float f; unsigned int i; } c;
    c.f = x;
    unsigned int r = c.i + 0x7FFFu + ((c.i >> 16) & 1u);   // RNE
    return (unsigned short)(r >> 16);
}

// --- edge-index dtype detection, sampled (single block, no atomics) ---------
__global__ void k_detect(const int* __restrict__ ei, int E, int* __restrict__ flag) {
    __shared__ int anyv[4];
    int t = threadIdx.x;                 // 256 threads, 4 samples each
    int v = 0;
#pragma unroll
    for (int r = 0; r < 4; ++r) {
        long long k = (long long)(t * 4 + r) * E >> 10;   // spread over [0,E)
        v |= ei[2 * (int)k + 1];
    }
    unsigned long long m = __ballot(v != 0);
    if ((t & 63) == 0) anyv[t >> 6] = (m != 0ull) ? 1 : 0;
    __syncthreads();
    if (t == 0) flag[0] = anyv[0] | anyv[1] | anyv[2] | anyv[3];
}

__device__ __forceinline__ int edge_idx(const void* ei, int is64, int which,
                                        int E, int e) {
    if (is64) return (int)((const long long*)ei)[(size_t)which * E + e];
    return ((const int*)ei)[(size_t)which * E + e];
}

// --- degree counting (int) --------------------------------------------------
__global__ void k_zero_int(int* p, int n) {
    int i = blockIdx.x * 256 + threadIdx.x;
    if (i < n) p[i] = 0;
}

__global__ void k_count(const void* __restrict__ ei, const int* __restrict__ flag,
                        int* __restrict__ counts, int E) {
    int e = blockIdx.x * 256 + threadIdx.x;
    if (e >= E) return;
    int is64 = (*flag == 0);
    int d = edge_idx(ei, is64, 1, E, e);
    atomicAdd(&counts[d], 1);
}

__global__ void k_dinv(const int* __restrict__ counts, float* __restrict__ dinv,
                       int n) {
    int i = blockIdx.x * 256 + threadIdx.x;
    if (i < n) dinv[i] = rsqrtf(1.0f + (float)counts[i]);
}

// --- exclusive scan over counts (3 kernels) ---------------------------------
__global__ void k_scan1(const int* __restrict__ counts, int* __restrict__ offs,
                        int* __restrict__ blockSums, int n) {
    __shared__ int tmp[256];
    int t = threadIdx.x;
    int i = blockIdx.x * 256 + t;
    int my = (i < n) ? counts[i] : 0;
    tmp[t] = my;
    __syncthreads();
    for (int off = 1; off < 256; off <<= 1) {
        int v = (t >= off) ? tmp[t - off] : 0;
        __syncthreads();
        tmp[t] += v;
        __syncthreads();
    }
    if (i < n) offs[i] = tmp[t] - my;
    if (t == 255) blockSums[blockIdx.x] = tmp[255];
}

// single-block 512-thread Hillis-Steele scan (exclusive), carry over tiles
__global__ void k_scan2(int* __restrict__ blockSums, int nb) {
    __shared__ int tmp[512];
    __shared__ int carry;
    int t = threadIdx.x;
    if (t == 0) carry = 0;
    __syncthreads();
    for (int base = 0; base < nb; base += 512) {
        int i = base + t;
        int my = (i < nb) ? blockSums[i] : 0;
        tmp[t] = my;
        __syncthreads();
        for (int off = 1; off < 512; off <<= 1) {
            int v = (t >= off) ? tmp[t - off] : 0;
            __syncthreads();
            tmp[t] += v;
            __syncthreads();
        }
        if (i < nb) blockSums[i] = carry + tmp[t] - my;   // exclusive
        __syncthreads();
        if (t == 0) carry += tmp[511];
        __syncthreads();
    }
}

__global__ void k_scan3(int* __restrict__ offs, const int* __restrict__ blockSums,
                        int* __restrict__ cursor, int n) {
    int i = blockIdx.x * 256 + threadIdx.x;
    if (i < n) {
        int o = offs[i] + blockSums[blockIdx.x];
        offs[i] = o;
        cursor[i] = o;
    }
}

__global__ void k_fill_csr(const void* __restrict__ ei, const int* __restrict__ flag,
                           int* __restrict__ cursor, int* __restrict__ csr, int E) {
    int e = blockIdx.x * 256 + threadIdx.x;
    if (e >= E) return;
    int is64 = (*flag == 0);
    int s = edge_idx(ei, is64, 0, E, e);
    int d = edge_idx(ei, is64, 1, E, e);
    int pos = atomicAdd(&cursor[d], 1);
    csr[pos] = s;
}

// --- conversions ------------------------------------------------------------
__global__ void k_cvt_x(const float* __restrict__ x, unsigned short* __restrict__ xb,
                        int n4) {
    int i = blockIdx.x * 256 + threadIdx.x;
    if (i >= n4) return;
    float4 v = reinterpret_cast<const float4*>(x)[i];
    ushort4 o;
    o.x = f2b(v.x); o.y = f2b(v.y); o.z = f2b(v.z); o.w = f2b(v.w);
    reinterpret_cast<ushort4*>(xb)[i] = o;
}

// W[k][n] (f32, KIN=128 rows, KOUT cols) -> WT[n][k] (bf16)
__global__ void k_cvt_wt(const float* __restrict__ W, unsigned short* __restrict__ WT,
                         int KOUT, int total) {
    int idx = blockIdx.x * 256 + threadIdx.x;
    if (idx >= total) return;
    int k = idx / KOUT, n = idx % KOUT;
    WT[(size_t)n * 128 + k] = f2b(W[idx]);
}

// --- CSR gather (bf16 rows, f32 accum): g[d] = dd^2 h[d] + sum dinv[s] dd h[s]
// 16 lanes/node, short8 (16B) loads; 16 nodes per 256-thread block.
__global__ __launch_bounds__(256) void k_gather_b(const unsigned short* __restrict__ h,
                                                  const float* __restrict__ dinv,
                                                  const int* __restrict__ offs,
                                                  const int* __restrict__ counts,
                                                  const int* __restrict__ csr,
                                                  unsigned short* __restrict__ g,
                                                  int N) {
    int node = blockIdx.x * 16 + (threadIdx.x >> 4);
    int l16 = threadIdx.x & 15;         // 8 bf16 (16B) per lane, 16 lanes = 256B row
    if (node >= N) return;
    const short8* h8 = reinterpret_cast<const short8*>(h);
    float dd = dinv[node];
    float w0 = dd * dd;
    size_t rowu = (size_t)node * 16 + l16;
    short8 sv = h8[rowu];
    float a[8];
#pragma unroll
    for (int j = 0; j < 8; ++j) a[j] = b2f((unsigned short)sv[j]) * w0;
    int beg = offs[node], cnt = counts[node];
    for (int e = 0; e < cnt; ++e) {
        int s = csr[beg + e];
        float w = dinv[s] * dd;
        short8 v = h8[(size_t)s * 16 + l16];
#pragma unroll
        for (int j = 0; j < 8; ++j) a[j] = fmaf(b2f((unsigned short)v[j]), w, a[j]);
    }
    short8 o;
#pragma unroll
    for (int j = 0; j < 8; ++j) o[j] = (short)f2b(a[j]);
    reinterpret_cast<short8*>(g)[rowu] = o;
}

// --- B-stationary MFMA GEMM -------------------------------------------------
// A[N,128]bf16 @ WT^T; 256 thr = 4 waves; wave owns cols [wave*KOUT/4, +KOUT/4).
// B fragments live in registers for the whole kernel (NFW*4 short8).
// Each block processes CHUNK row-tiles of 16 rows.
// Fragment mapping (16x16x32, m89-verified): A: row=lane&15, k=(lane>>4)*8+j;
// B: col=lane&15 (WT row), same k; D: col=lane&15, row=(lane>>4)*4+r.
template <int KOUT, bool REDUCE, int CHUNK>
__global__ __launch_bounds__(256) void k_mgemm(const unsigned short* __restrict__ A,
                                               const unsigned short* __restrict__ WT,
                                               const float* __restrict__ bias,
                                               unsigned short* __restrict__ C,
                                               float* __restrict__ partials, int N) {
    constexpr int NFW = KOUT / 64;       // col-frags per wave (2 or 4)
    const int tid = threadIdx.x;
    const int wave = tid >> 6, lane = tid & 63;
    const int l15 = lane & 15, lg = lane >> 4;
    const int colbase = wave * (KOUT / 4);

    // stage B into registers (once)
    short8 breg[NFW][4];
    float bv[NFW];
#pragma unroll
    for (int nf = 0; nf < NFW; ++nf) {
        int col = colbase + nf * 16 + l15;
        bv[nf] = bias[col];
#pragma unroll
        for (int kk = 0; kk < 4; ++kk)
            breg[nf][kk] = *reinterpret_cast<const short8*>(
                WT + (size_t)col * 128 + kk * 32 + lg * 8);
    }

    float psum[NFW];
#pragma unroll
    for (int nf = 0; nf < NFW; ++nf) psum[nf] = 0.f;

    const int NT = (N + 15) / 16;
    const int t0 = blockIdx.x * CHUNK;
    const int tend = (t0 + CHUNK < NT) ? t0 + CHUNK : NT;

#pragma unroll 2
    for (int t = t0; t < tend; ++t) {
        const int rows = t * 16;
        const int arow = rows + l15;
        short8 a[4];
        const bool rv = arow < N;
#pragma unroll
        for (int kk = 0; kk < 4; ++kk)
            a[kk] = rv ? *reinterpret_cast<const short8*>(
                             A + (size_t)arow * 128 + kk * 32 + lg * 8)
                       : (short8){0, 0, 0, 0, 0, 0, 0, 0};

        f32x4 acc[NFW];
#pragma unroll
        for (int nf = 0; nf < NFW; ++nf) acc[nf] = (f32x4){0.f, 0.f, 0.f, 0.f};
#pragma unroll
        for (int kk = 0; kk < 4; ++kk)
#pragma unroll
            for (int nf = 0; nf < NFW; ++nf)
                acc[nf] = __builtin_amdgcn_mfma_f32_16x16x32_bf16(
                    a[kk], breg[nf][kk], acc[nf], 0, 0, 0);

        if (!REDUCE) {
#pragma unroll
            for (int nf = 0; nf < NFW; ++nf) {
                int col = colbase + nf * 16 + l15;
#pragma unroll
                for (int r = 0; r < 4; ++r) {
                    int rr = rows + lg * 4 + r;
                    if (rr < N)
                        C[(size_t)rr * KOUT + col] =
                            f2b(fmaxf(acc[nf][r] + bv[nf], 0.f));
                }
            }
        } else {
#pragma unroll
            for (int nf = 0; nf < NFW; ++nf) {
#pragma unroll
                for (int r = 0; r < 4; ++r) {
                    int rr = rows + lg * 4 + r;
                    if (rr < N) psum[nf] += fmaxf(acc[nf][r] + bv[nf], 0.f);
                }
            }
        }
    }

    if (REDUCE) {
#pragma unroll
        for (int nf = 0; nf < NFW; ++nf) {
            float s = psum[nf];
            s += __shfl_xor(s, 16);
            s += __shfl_xor(s, 32);
            if (lg == 0)
                partials[(size_t)blockIdx.x * KOUT + colbase + nf * 16 + l15] = s;
        }
    }
}

// --- partials reduction: [NB][256] -> [16][256] -> out[256]*invN ------------
__global__ void k_reduce1(const float* __restrict__ partials, float* __restrict__ p2,
                          int NB) {
    int c = threadIdx.x;
    float sum = 0.f;
    for (int r = blockIdx.x; r < NB; r += 16)
        sum += partials[(size_t)r * 256 + c];
    p2[blockIdx.x * 256 + c] = sum;
}

__global__ void k_reduce2(const float* __restrict__ p2, float* __restrict__ out,
                          float invN) {
    int c = threadIdx.x;
    float sum = 0.f;
#pragma unroll
    for (int b = 0; b < 16; ++b) sum += p2[b * 256 + c];
    out[c] = sum * invN;
}

// ---------------------------------------------------------------------------
extern "C" void kernel_launch(void* const* d_in, const int* in_sizes, int n_in,
                              void* d_out, int out_size, void* d_ws, size_t ws_size,
                              hipStream_t stream) {
    const float* x  = (const float*)d_in[0];
    const void*  ei = d_in[1];
    const float* W1 = (const float*)d_in[2];
    const float* b1 = (const float*)d_in[3];
    const float* W2 = (const float*)d_in[4];
    const float* b2 = (const float*)d_in[5];
    float* out = (float*)d_out;

    const int N = in_sizes[0] / 128;   // 100000
    const int E = in_sizes[1] / 2;     // 600000
    const int nb = (N + 255) / 256;
    constexpr int CHUNK = 8;           // row-tiles (16 rows) per gemm block
    const int NT = (N + 15) / 16;
    const int NBLK = (NT + CHUNK - 1) / CHUNK;   // gemm blocks (782)

    char* ws = (char*)d_ws;
    size_t off = 0;
    auto alloc = [&](size_t bytes) {
        char* p = ws + off;
        off += (bytes + 255) & ~(size_t)255;
        return p;
    };
    int*            flag      = (int*)alloc(4);
    int*            counts    = (int*)alloc((size_t)N * 4);
    int*            offs      = (int*)alloc((size_t)N * 4);
    int*            cursor    = (int*)alloc((size_t)N * 4);
    int*            blockSums = (int*)alloc((size_t)nb * 4);
    float*          dinv      = (float*)alloc((size_t)N * 4);
    int*            csr       = (int*)alloc((size_t)E * 4);
    float*          partials  = (float*)alloc((size_t)NBLK * 256 * 4);
    float*          p2        = (float*)alloc((size_t)16 * 256 * 4);
    unsigned short* wt1       = (unsigned short*)alloc((size_t)128 * 128 * 2);
    unsigned short* wt2       = (unsigned short*)alloc((size_t)256 * 128 * 2);
    unsigned short* xb        = (unsigned short*)alloc((size_t)N * 128 * 2);
    unsigned short* g1        = (unsigned short*)alloc((size_t)N * 128 * 2);
    unsigned short* a1r       = (unsigned short*)alloc((size_t)N * 128 * 2);
    unsigned short* g2        = xb;    // xb dead after gather1

    // --- edge dtype detection + degrees + CSR ---
    k_detect<<<1, 256, 0, stream>>>((const int*)ei, E, flag);
    k_zero_int<<<nb, 256, 0, stream>>>(counts, N);
    k_count<<<(E + 255) / 256, 256, 0, stream>>>(ei, flag, counts, E);
    k_dinv<<<nb, 256, 0, stream>>>(counts, dinv, N);
    k_scan1<<<nb, 256, 0, stream>>>(counts, offs, blockSums, N);
    k_scan2<<<1, 512, 0, stream>>>(blockSums, nb);
    k_scan3<<<nb, 256, 0, stream>>>(offs, blockSums, cursor, N);
    k_fill_csr<<<(E + 255) / 256, 256, 0, stream>>>(ei, flag, cursor, csr, E);

    // --- conversions ---
    k_cvt_x<<<(N * 32 + 255) / 256, 256, 0, stream>>>(x, xb, N * 32);
    k_cvt_wt<<<(128 * 128 + 255) / 256, 256, 0, stream>>>(W1, wt1, 128, 128 * 128);
    k_cvt_wt<<<(128 * 256 + 255) / 256, 256, 0, stream>>>(W2, wt2, 256, 128 * 256);

    // --- layer 1 ---
    k_gather_b<<<(N + 15) / 16, 256, 0, stream>>>(xb, dinv, offs, counts, csr, g1, N);
    k_mgemm<128, false, CHUNK><<<NBLK, 256, 0, stream>>>(g1, wt1, b1, a1r, nullptr, N);

    // --- layer 2 + fused mean ---
    k_gather_b<<<(N + 15) / 16, 256, 0, stream>>>(a1r, dinv, offs, counts, csr, g2, N);
    k_mgemm<256, true, CHUNK><<<NBLK, 256, 0, stream>>>(g2, wt2, b2, nullptr, partials, N);
    k_reduce1<<<16, 256, 0, stream>>>(partials, p2, NBLK);
    k_reduce2<<<1, 256, 0, stream>>>(p2, out, 1.0f / (float)N);
}

// Round 8
// 219.467 us; speedup vs baseline: 21.3987x; 1.0964x over previous
//
#include <hip/hip_runtime.h>

// ---------------------------------------------------------------------------
// DrugGCN, bf16-MFMA pipeline (R8):
//   CSR by dst with FUSED edge weights: csr2[pos] = {src, dinv[s]*dinv[d]}.
//   xb  = bf16(x)
//   g1  = A_hat xb           (software-pipelined CSR gather, f32 accum)
//   a1r = relu(g1@W1 + b1)   (B-stationary MFMA GEMM)
//   g2  = A_hat a1r          (gather)
//   out = mean_rows relu(g2@W2 + b2)  (B-stationary GEMM, fused col-reduce)
// R7 lesson: gather was the top cost (45us, VALU 17%, 2.5TB/s) — per-edge
// chain csr->dinv->row = 2-3 serial latencies. Now: one 8B pair load + row
// load, 1-ahead pipelined; weights precomputed in fill.
// ---------------------------------------------------------------------------

typedef __attribute__((ext_vector_type(8))) short short8;
typedef __attribute__((ext_vector_type(4))) float f32x4;

__device__ __forceinline__ float b2f(unsigned short u) {
    union { unsigned int i; float f; } c;
    c.i = ((unsigned int)u) << 16;
    return c.f;
}
__device__ __forceinline__ unsigned short f2b(float x) {
    union { float f; unsigned int i; } c;
    c.f = x;
    unsigned int r = c.i + 0x7FFFu + ((c.i >> 16) & 1u);   // RNE
    return (unsigned short)(r >> 16);
}

// --- edge-index dtype detection, sampled (single block, no atomics) ---------
__global__ void k_detect(const int* __restrict__ ei, int E, int* __restrict__ flag) {
    __shared__ int anyv[4];
    int t = threadIdx.x;                 // 256 threads, 4 samples each
    int v = 0;
#pragma unroll
    for (int r = 0; r < 4; ++r) {
        long long k = (long long)(t * 4 + r) * E >> 10;   // spread over [0,E)
        v |= ei[2 * (int)k + 1];
    }
    unsigned long long m = __ballot(v != 0);
    if ((t & 63) == 0) anyv[t >> 6] = (m != 0ull) ? 1 : 0;
    __syncthreads();
    if (t == 0) flag[0] = anyv[0] | anyv[1] | anyv[2] | anyv[3];
}

__device__ __forceinline__ int edge_idx(const void* ei, int is64, int which,
                                        int E, int e) {
    if (is64) return (int)((const long long*)ei)[(size_t)which * E + e];
    return ((const int*)ei)[(size_t)which * E + e];
}

__global__ void k_count(const void* __restrict__ ei, const int* __restrict__ flag,
                        int* __restrict__ counts, int E) {
    int e = blockIdx.x * 256 + threadIdx.x;
    if (e >= E) return;
    int is64 = (*flag == 0);
    int d = edge_idx(ei, is64, 1, E, e);
    atomicAdd(&counts[d], 1);
}

// --- scan1 (+ fused dinv): per-block exclusive scan of counts ---------------
__global__ void k_scan1(const int* __restrict__ counts, int* __restrict__ offs,
                        int* __restrict__ blockSums, float* __restrict__ dinv,
                        int n) {
    __shared__ int tmp[256];
    int t = threadIdx.x;
    int i = blockIdx.x * 256 + t;
    int my = (i < n) ? counts[i] : 0;
    if (i < n) dinv[i] = rsqrtf(1.0f + (float)my);
    tmp[t] = my;
    __syncthreads();
    for (int off = 1; off < 256; off <<= 1) {
        int v = (t >= off) ? tmp[t - off] : 0;
        __syncthreads();
        tmp[t] += v;
        __syncthreads();
    }
    if (i < n) offs[i] = tmp[t] - my;
    if (t == 255) blockSums[blockIdx.x] = tmp[255];
}

// single-block 512-thread Hillis-Steele scan (exclusive), carry over tiles
__global__ void k_scan2(int* __restrict__ blockSums, int nb) {
    __shared__ int tmp[512];
    __shared__ int carry;
    int t = threadIdx.x;
    if (t == 0) carry = 0;
    __syncthreads();
    for (int base = 0; base < nb; base += 512) {
        int i = base + t;
        int my = (i < nb) ? blockSums[i] : 0;
        tmp[t] = my;
        __syncthreads();
        for (int off = 1; off < 512; off <<= 1) {
            int v = (t >= off) ? tmp[t - off] : 0;
            __syncthreads();
            tmp[t] += v;
            __syncthreads();
        }
        if (i < nb) blockSums[i] = carry + tmp[t] - my;   // exclusive
        __syncthreads();
        if (t == 0) carry += tmp[511];
        __syncthreads();
    }
}

__global__ void k_scan3(int* __restrict__ offs, const int* __restrict__ blockSums,
                        int* __restrict__ cursor, int n) {
    int i = blockIdx.x * 256 + threadIdx.x;
    if (i < n) {
        int o = offs[i] + blockSums[blockIdx.x];
        offs[i] = o;
        cursor[i] = o;
    }
}

// --- CSR fill with fused weights: csr2[pos] = {s, dinv[s]*dinv[d]} ----------
__global__ void k_fill_csr(const void* __restrict__ ei, const int* __restrict__ flag,
                           const float* __restrict__ dinv, int* __restrict__ cursor,
                           int2* __restrict__ csr2, int E) {
    int e = blockIdx.x * 256 + threadIdx.x;
    if (e >= E) return;
    int is64 = (*flag == 0);
    int s = edge_idx(ei, is64, 0, E, e);
    int d = edge_idx(ei, is64, 1, E, e);
    int pos = atomicAdd(&cursor[d], 1);
    csr2[pos] = make_int2(s, __float_as_int(dinv[s] * dinv[d]));
}

// --- conversions ------------------------------------------------------------
__global__ void k_cvt_x(const float* __restrict__ x, unsigned short* __restrict__ xb,
                        int n4) {
    int i = blockIdx.x * 256 + threadIdx.x;
    if (i >= n4) return;
    float4 v = reinterpret_cast<const float4*>(x)[i];
    ushort4 o;
    o.x = f2b(v.x); o.y = f2b(v.y); o.z = f2b(v.z); o.w = f2b(v.w);
    reinterpret_cast<ushort4*>(xb)[i] = o;
}

// W[k][n] (f32, KIN=128 rows, KOUT cols) -> WT[n][k] (bf16)
__global__ void k_cvt_wt(const float* __restrict__ W, unsigned short* __restrict__ WT,
                         int KOUT, int total) {
    int idx = blockIdx.x * 256 + threadIdx.x;
    if (idx >= total) return;
    int k = idx / KOUT, n = idx % KOUT;
    WT[(size_t)n * 128 + k] = f2b(W[idx]);
}

// --- CSR gather, software-pipelined -----------------------------------------
// g[d] = dd^2 h[d] + sum_e w_e h[s_e];  16 lanes/node (short8 = 16B/lane),
// 16 groups/block, CHUNK nodes per group. 1-ahead prefetch of (pair, row).
template <int CHUNK>
__global__ __launch_bounds__(256) void k_gather_b(const unsigned short* __restrict__ h,
                                                  const float* __restrict__ dinv,
                                                  const int* __restrict__ offs,
                                                  const int* __restrict__ counts,
                                                  const int2* __restrict__ csr2,
                                                  unsigned short* __restrict__ g,
                                                  int N) {
    const int grp = threadIdx.x >> 4, l16 = threadIdx.x & 15;
    const short8* h8 = reinterpret_cast<const short8*>(h);
    const int base = blockIdx.x * (CHUNK * 16) + grp;

    for (int i = 0; i < CHUNK; ++i) {
        const int node = base + i * 16;
        if (node >= N) break;               // uniform across the 16-lane group
        const float dd = dinv[node];
        const float w0 = dd * dd;
        const size_t rowu = (size_t)node * 16 + l16;
        short8 sv = h8[rowu];
        float a[8];
#pragma unroll
        for (int j = 0; j < 8; ++j) a[j] = b2f((unsigned short)sv[j]) * w0;

        const int beg = offs[node], cnt = counts[node];
        if (cnt > 0) {
            int2 p = csr2[beg];
            short8 v = h8[(size_t)p.x * 16 + l16];
            for (int e = 1; e < cnt; ++e) {
                int2 pn = csr2[beg + e];                       // next pair
                short8 vn = h8[(size_t)pn.x * 16 + l16];       // next row (issued
                float w = __int_as_float(p.y);                 //  before acc wait)
#pragma unroll
                for (int j = 0; j < 8; ++j)
                    a[j] = fmaf(b2f((unsigned short)v[j]), w, a[j]);
                p = pn; v = vn;
            }
            float w = __int_as_float(p.y);
#pragma unroll
            for (int j = 0; j < 8; ++j)
                a[j] = fmaf(b2f((unsigned short)v[j]), w, a[j]);
        }
        short8 o;
#pragma unroll
        for (int j = 0; j < 8; ++j) o[j] = (short)f2b(a[j]);
        reinterpret_cast<short8*>(g)[rowu] = o;
    }
}

// --- B-stationary MFMA GEMM (unchanged from R7) -----------------------------
template <int KOUT, bool REDUCE, int CHUNK>
__global__ __launch_bounds__(256) void k_mgemm(const unsigned short* __restrict__ A,
                                               const unsigned short* __restrict__ WT,
                                               const float* __restrict__ bias,
                                               unsigned short* __restrict__ C,
                                               float* __restrict__ partials, int N) {
    constexpr int NFW = KOUT / 64;       // col-frags per wave (2 or 4)
    const int tid = threadIdx.x;
    const int wave = tid >> 6, lane = tid & 63;
    const int l15 = lane & 15, lg = lane >> 4;
    const int colbase = wave * (KOUT / 4);

    short8 breg[NFW][4];
    float bv[NFW];
#pragma unroll
    for (int nf = 0; nf < NFW; ++nf) {
        int col = colbase + nf * 16 + l15;
        bv[nf] = bias[col];
#pragma unroll
        for (int kk = 0; kk < 4; ++kk)
            breg[nf][kk] = *reinterpret_cast<const short8*>(
                WT + (size_t)col * 128 + kk * 32 + lg * 8);
    }

    float psum[NFW];
#pragma unroll
    for (int nf = 0; nf < NFW; ++nf) psum[nf] = 0.f;

    const int NT = (N + 15) / 16;
    const int t0 = blockIdx.x * CHUNK;
    const int tend = (t0 + CHUNK < NT) ? t0 + CHUNK : NT;

#pragma unroll 2
    for (int t = t0; t < tend; ++t) {
        const int rows = t * 16;
        const int arow = rows + l15;
        short8 a[4];
        const bool rv = arow < N;
#pragma unroll
        for (int kk = 0; kk < 4; ++kk)
            a[kk] = rv ? *reinterpret_cast<const short8*>(
                             A + (size_t)arow * 128 + kk * 32 + lg * 8)
                       : (short8){0, 0, 0, 0, 0, 0, 0, 0};

        f32x4 acc[NFW];
#pragma unroll
        for (int nf = 0; nf < NFW; ++nf) acc[nf] = (f32x4){0.f, 0.f, 0.f, 0.f};
#pragma unroll
        for (int kk = 0; kk < 4; ++kk)
#pragma unroll
            for (int nf = 0; nf < NFW; ++nf)
                acc[nf] = __builtin_amdgcn_mfma_f32_16x16x32_bf16(
                    a[kk], breg[nf][kk], acc[nf], 0, 0, 0);

        if (!REDUCE) {
#pragma unroll
            for (int nf = 0; nf < NFW; ++nf) {
                int col = colbase + nf * 16 + l15;
#pragma unroll
                for (int r = 0; r < 4; ++r) {
                    int rr = rows + lg * 4 + r;
                    if (rr < N)
                        C[(size_t)rr * KOUT + col] =
                            f2b(fmaxf(acc[nf][r] + bv[nf], 0.f));
                }
            }
        } else {
#pragma unroll
            for (int nf = 0; nf < NFW; ++nf) {
#pragma unroll
                for (int r = 0; r < 4; ++r) {
                    int rr = rows + lg * 4 + r;
                    if (rr < N) psum[nf] += fmaxf(acc[nf][r] + bv[nf], 0.f);
                }
            }
        }
    }

    if (REDUCE) {
#pragma unroll
        for (int nf = 0; nf < NFW; ++nf) {
            float s = psum[nf];
            s += __shfl_xor(s, 16);
            s += __shfl_xor(s, 32);
            if (lg == 0)
                partials[(size_t)blockIdx.x * KOUT + colbase + nf * 16 + l15] = s;
        }
    }
}

// --- partials reduction: [NB][256] -> [16][256] -> out[256]*invN ------------
__global__ void k_reduce1(const float* __restrict__ partials, float* __restrict__ p2,
                          int NB) {
    int c = threadIdx.x;
    float sum = 0.f;
    for (int r = blockIdx.x; r < NB; r += 16)
        sum += partials[(size_t)r * 256 + c];
    p2[blockIdx.x * 256 + c] = sum;
}

__global__ void k_reduce2(const float* __restrict__ p2, float* __restrict__ out,
                          float invN) {
    int c = threadIdx.x;
    float sum = 0.f;
#pragma unroll
    for (int b = 0; b < 16; ++b) sum += p2[b * 256 + c];
    out[c] = sum * invN;
}

// ---------------------------------------------------------------------------
extern "C" void kernel_launch(void* const* d_in, const int* in_sizes, int n_in,
                              void* d_out, int out_size, void* d_ws, size_t ws_size,
                              hipStream_t stream) {
    const float* x  = (const float*)d_in[0];
    const void*  ei = d_in[1];
    const float* W1 = (const float*)d_in[2];
    const float* b1 = (const float*)d_in[3];
    const float* W2 = (const float*)d_in[4];
    const float* b2 = (const float*)d_in[5];
    float* out = (float*)d_out;

    const int N = in_sizes[0] / 128;   // 100000
    const int E = in_sizes[1] / 2;     // 600000
    const int nb = (N + 255) / 256;
    constexpr int GCHUNK = 4;          // nodes per 16-lane group in gather
    constexpr int MCHUNK = 8;          // row-tiles per gemm block
    const int NT = (N + 15) / 16;
    const int NBLK = (NT + MCHUNK - 1) / MCHUNK;     // gemm blocks
    const int GBLK = (N + GCHUNK * 16 - 1) / (GCHUNK * 16);  // gather blocks

    char* ws = (char*)d_ws;
    size_t off = 0;
    auto alloc = [&](size_t bytes) {
        char* p = ws + off;
        off += (bytes + 255) & ~(size_t)255;
        return p;
    };
    int*            flag      = (int*)alloc(4);
    int*            counts    = (int*)alloc((size_t)N * 4);
    int*            offs      = (int*)alloc((size_t)N * 4);
    int*            cursor    = (int*)alloc((size_t)N * 4);
    int*            blockSums = (int*)alloc((size_t)nb * 4);
    float*          dinv      = (float*)alloc((size_t)N * 4);
    int2*           csr2      = (int2*)alloc((size_t)E * 8);
    float*          partials  = (float*)alloc((size_t)NBLK * 256 * 4);
    float*          p2        = (float*)alloc((size_t)16 * 256 * 4);
    unsigned short* wt1       = (unsigned short*)alloc((size_t)128 * 128 * 2);
    unsigned short* wt2       = (unsigned short*)alloc((size_t)256 * 128 * 2);
    unsigned short* xb        = (unsigned short*)alloc((size_t)N * 128 * 2);
    unsigned short* g1        = (unsigned short*)alloc((size_t)N * 128 * 2);
    unsigned short* a1r       = (unsigned short*)alloc((size_t)N * 128 * 2);
    unsigned short* g2        = xb;    // xb dead after gather1

    // --- edge dtype detection + degrees + CSR(+weights) ---
    k_detect<<<1, 256, 0, stream>>>((const int*)ei, E, flag);
    hipMemsetAsync(counts, 0, (size_t)N * 4, stream);
    k_count<<<(E + 255) / 256, 256, 0, stream>>>(ei, flag, counts, E);
    k_scan1<<<nb, 256, 0, stream>>>(counts, offs, blockSums, dinv, N);
    k_scan2<<<1, 512, 0, stream>>>(blockSums, nb);
    k_scan3<<<nb, 256, 0, stream>>>(offs, blockSums, cursor, N);
    k_fill_csr<<<(E + 255) / 256, 256, 0, stream>>>(ei, flag, dinv, cursor, csr2, E);

    // --- conversions ---
    k_cvt_x<<<(N * 32 + 255) / 256, 256, 0, stream>>>(x, xb, N * 32);
    k_cvt_wt<<<(128 * 128 + 255) / 256, 256, 0, stream>>>(W1, wt1, 128, 128 * 128);
    k_cvt_wt<<<(128 * 256 + 255) / 256, 256, 0, stream>>>(W2, wt2, 256, 128 * 256);

    // --- layer 1 ---
    k_gather_b<GCHUNK><<<GBLK, 256, 0, stream>>>(xb, dinv, offs, counts, csr2, g1, N);
    k_mgemm<128, false, MCHUNK><<<NBLK, 256, 0, stream>>>(g1, wt1, b1, a1r, nullptr, N);

    // --- layer 2 + fused mean ---
    k_gather_b<GCHUNK><<<GBLK, 256, 0, stream>>>(a1r, dinv, offs, counts, csr2, g2, N);
    k_mgemm<256, true, MCHUNK><<<NBLK, 256, 0, stream>>>(g2, wt2, b2, nullptr, partials, N);
    k_reduce1<<<16, 256, 0, stream>>>(partials, p2, NBLK);
    k_reduce2<<<1, 256, 0, stream>>>(p2, out, 1.0f / (float)N);
}